// Round 1
// baseline (1031.409 us; speedup 1.0000x reference)
//
#include <hip/hip_runtime.h>
#include <math.h>

#define CC   64
#define BATCH 2048
#define EPS  1e-5f
#define SLOPE 0.01f

// ws layout (floats):
// [0,128)        : sum per (c,o)
// [128,256)      : sumsq per (c,o)
// [256,2304)     : logits (2048)
// [2304,2432)    : A (BN scale) per (c,o)
// [2432,2560)    : Bsh (BN shift) per (c,o)
// [2560,10752)   : wfold [c][128]
// [10752,10816)  : wb per c (bias contribution)
#define WS_SUM   0
#define WS_SQ    128
#define WS_LOGIT 256
#define WS_A     2304
#define WS_B     2432
#define WS_WF    2560
#define WS_WB    10752

// ---------------- Pass 1: conv + batch stats ----------------
__global__ __launch_bounds__(128) void stats_kernel(
    const float* __restrict__ x1, const float* __restrict__ x2,
    const float* __restrict__ conv_w, const float* __restrict__ conv_b,
    float* __restrict__ ws)
{
    __shared__ float lds[2 * 361];
    __shared__ float red[2][4];

    int blk = blockIdx.x;
    int c = blk & 63;
    int b = blk >> 6;

    const float* src1 = x1 + ((size_t)b * CC + c) * 361;
    const float* src2 = x2 + ((size_t)b * CC + c) * 361;
    for (int i = threadIdx.x; i < 361; i += 128) {
        lds[i]       = src1[i];
        lds[361 + i] = src2[i];
    }

    // conv weights for this c: [2][2][3][3] ; uniform addresses -> cached
    const float* wcp = conv_w + c * 36;
    float w[2][2][3][3];
    #pragma unroll
    for (int o = 0; o < 2; o++)
        #pragma unroll
        for (int ic = 0; ic < 2; ic++)
            #pragma unroll
            for (int ki = 0; ki < 3; ki++)
                #pragma unroll
                for (int kj = 0; kj < 3; kj++)
                    w[o][ic][ki][kj] = wcp[((o * 2 + ic) * 3 + ki) * 3 + kj];
    float cb[2] = { conv_b[c * 2 + 0], conv_b[c * 2 + 1] };

    __syncthreads();

    float s0 = 0.f, q0 = 0.f, s1 = 0.f, q1 = 0.f;
    #pragma unroll
    for (int o = 0; o < 2; o++) {
        for (int t = threadIdx.x; t < 289; t += 128) {
            int i = t / 17;
            int j = t - i * 17;
            float acc = cb[o];
            #pragma unroll
            for (int ic = 0; ic < 2; ic++) {
                const float* base = &lds[ic * 361 + i * 19 + j];
                #pragma unroll
                for (int ki = 0; ki < 3; ki++)
                    #pragma unroll
                    for (int kj = 0; kj < 3; kj++)
                        acc += base[ki * 19 + kj] * w[o][ic][ki][kj];
            }
            if (o == 0) { s0 += acc; q0 += acc * acc; }
            else        { s1 += acc; q1 += acc * acc; }
        }
    }

    // wave reduce (64 lanes)
    #pragma unroll
    for (int off = 32; off > 0; off >>= 1) {
        s0 += __shfl_down(s0, off);
        q0 += __shfl_down(q0, off);
        s1 += __shfl_down(s1, off);
        q1 += __shfl_down(q1, off);
    }
    int wid  = threadIdx.x >> 6;
    int lane = threadIdx.x & 63;
    if (lane == 0) {
        red[wid][0] = s0; red[wid][1] = q0; red[wid][2] = s1; red[wid][3] = q1;
    }
    __syncthreads();
    if (threadIdx.x == 0) {
        atomicAdd(&ws[WS_SUM + c * 2 + 0], red[0][0] + red[1][0]);
        atomicAdd(&ws[WS_SQ  + c * 2 + 0], red[0][1] + red[1][1]);
        atomicAdd(&ws[WS_SUM + c * 2 + 1], red[0][2] + red[1][2]);
        atomicAdd(&ws[WS_SQ  + c * 2 + 1], red[0][3] + red[1][3]);
    }
}

// ---------------- Prep: BN scale/shift + folded fc weights ----------------
__global__ __launch_bounds__(128) void prep_kernel(
    const float* __restrict__ bn_g, const float* __restrict__ bn_b,
    const float* __restrict__ fc1_w, const float* __restrict__ fc1_b,
    const float* __restrict__ fc2_w, const float* __restrict__ fc2_b,
    const float* __restrict__ w_out,
    float* __restrict__ ws)
{
    int c = blockIdx.x;
    int f = threadIdx.x;

    float wsum = 0.f;
    #pragma unroll
    for (int h = 0; h < 8; h++)
        wsum += fc2_w[c * 8 + h] * fc1_w[(c * 8 + h) * 128 + f];
    ws[WS_WF + c * 128 + f] = w_out[c] * wsum;

    if (f == 0) {
        float bsum = fc2_b[c];
        #pragma unroll
        for (int h = 0; h < 8; h++)
            bsum += fc2_w[c * 8 + h] * fc1_b[c * 8 + h];
        ws[WS_WB + c] = w_out[c] * bsum;
    }
    if (f < 2) {
        int idx = c * 2 + f;
        const float N = 2048.0f * 289.0f;
        float mean = ws[WS_SUM + idx] / N;
        float var  = ws[WS_SQ + idx] / N - mean * mean;
        float inv  = rsqrtf(var + EPS);
        float A    = bn_g[idx] * inv;
        ws[WS_A + idx] = A;
        ws[WS_B + idx] = bn_b[idx] - mean * A;
    }
}

// ---------------- Pass 2: conv + BN + leaky + maxpool + folded dot ----------------
__global__ __launch_bounds__(128) void main_kernel(
    const float* __restrict__ x1, const float* __restrict__ x2,
    const float* __restrict__ conv_w, const float* __restrict__ conv_b,
    const float* __restrict__ ws)
{
    __shared__ float lds[2 * 361];
    __shared__ float red[2];

    int blk = blockIdx.x;
    int c = blk & 63;
    int b = blk >> 6;

    const float* src1 = x1 + ((size_t)b * CC + c) * 361;
    const float* src2 = x2 + ((size_t)b * CC + c) * 361;
    for (int i = threadIdx.x; i < 361; i += 128) {
        lds[i]       = src1[i];
        lds[361 + i] = src2[i];
    }

    int f  = threadIdx.x;          // pooled cell id 0..127
    int o  = f >> 6;               // wave-uniform
    int rem = f & 63;
    int pi = rem >> 3;
    int pj = rem & 7;

    // per-wave conv weights (o is wave-uniform -> no divergence)
    const float* wcp = conv_w + c * 36 + o * 18;
    float w[2][3][3];
    #pragma unroll
    for (int ic = 0; ic < 2; ic++)
        #pragma unroll
        for (int ki = 0; ki < 3; ki++)
            #pragma unroll
            for (int kj = 0; kj < 3; kj++)
                w[ic][ki][kj] = wcp[(ic * 3 + ki) * 3 + kj];
    float cbv = conv_b[c * 2 + o];
    float A   = ws[WS_A + c * 2 + o];
    float Bsh = ws[WS_B + c * 2 + o];
    float wf  = ws[WS_WF + c * 128 + f];

    __syncthreads();

    // 4x4 input window per ic into registers
    float xw[2][4][4];
    #pragma unroll
    for (int ic = 0; ic < 2; ic++)
        #pragma unroll
        for (int rr = 0; rr < 4; rr++)
            #pragma unroll
            for (int ccol = 0; ccol < 4; ccol++)
                xw[ic][rr][ccol] = lds[ic * 361 + (2 * pi + rr) * 19 + (2 * pj + ccol)];

    float m = -3.4e38f;
    #pragma unroll
    for (int di = 0; di < 2; di++)
        #pragma unroll
        for (int dj = 0; dj < 2; dj++) {
            float acc = cbv;
            #pragma unroll
            for (int ic = 0; ic < 2; ic++)
                #pragma unroll
                for (int ki = 0; ki < 3; ki++)
                    #pragma unroll
                    for (int kj = 0; kj < 3; kj++)
                        acc += xw[ic][di + ki][dj + kj] * w[ic][ki][kj];
            float v = acc * A + Bsh;
            v = v > 0.f ? v : SLOPE * v;
            m = fmaxf(m, v);
        }

    float contrib = m * wf;
    #pragma unroll
    for (int off = 32; off > 0; off >>= 1)
        contrib += __shfl_down(contrib, off);
    int wid  = threadIdx.x >> 6;
    int lane = threadIdx.x & 63;
    if (lane == 0) red[wid] = contrib;
    __syncthreads();
    if (threadIdx.x == 0)
        atomicAdd((float*)&ws[WS_LOGIT + b], red[0] + red[1]);
}

// ---------------- Final: sigmoid ----------------
__global__ __launch_bounds__(256) void final_kernel(
    const float* __restrict__ ws, const float* __restrict__ b_out,
    float* __restrict__ out)
{
    int b = blockIdx.x * blockDim.x + threadIdx.x;
    if (b >= BATCH) return;
    float bias = b_out[0];
    #pragma unroll
    for (int c = 0; c < CC; c++) bias += ws[WS_WB + c];
    float l = ws[WS_LOGIT + b] + bias;
    out[b] = 1.f / (1.f + expf(-l));
}

extern "C" void kernel_launch(void* const* d_in, const int* in_sizes, int n_in,
                              void* d_out, int out_size, void* d_ws, size_t ws_size,
                              hipStream_t stream) {
    const float* x1     = (const float*)d_in[0];
    const float* x2     = (const float*)d_in[1];
    const float* conv_w = (const float*)d_in[2];
    const float* conv_b = (const float*)d_in[3];
    const float* bn_g   = (const float*)d_in[4];
    const float* bn_b   = (const float*)d_in[5];
    const float* fc1_w  = (const float*)d_in[6];
    const float* fc1_b  = (const float*)d_in[7];
    const float* fc2_w  = (const float*)d_in[8];
    const float* fc2_b  = (const float*)d_in[9];
    const float* w_out  = (const float*)d_in[10];
    const float* b_out  = (const float*)d_in[11];
    float* ws  = (float*)d_ws;
    float* out = (float*)d_out;

    // zero the accumulators: sum/sumsq (256) + logits (2048)
    hipMemsetAsync(d_ws, 0, 2304 * sizeof(float), stream);

    dim3 big(BATCH * CC);
    stats_kernel<<<big, 128, 0, stream>>>(x1, x2, conv_w, conv_b, ws);
    prep_kernel<<<CC, 128, 0, stream>>>(bn_g, bn_b, fc1_w, fc1_b, fc2_w, fc2_b, w_out, ws);
    main_kernel<<<big, 128, 0, stream>>>(x1, x2, conv_w, conv_b, ws);
    final_kernel<<<(BATCH + 255) / 256, 256, 0, stream>>>(ws, b_out, out);
}

// Round 2
// 186.432 us; speedup vs baseline: 5.5324x; 5.5324x over previous
//
#include <hip/hip_runtime.h>
#include <math.h>

#define CC    64
#define BATCH 2048
#define EPS   1e-5f
#define SLOPE 0.01f

// ws layout (float indices):
#define WS_SUMR  0        // 32 replicas x 128 (c,o)
#define WS_SQR   4096     // 32 replicas x 128
#define WS_A     8192     // 128
#define WS_B     8320     // 128
#define WS_WF    8448     // 64*128 folded weights
#define WS_WB    16640    // 64 per-channel bias contribution
#define WS_LOGIT 16704    // 2048 (fallback path only)
#define WS_POOL  18944    // 2048*64*128 float2 = (max,min) per pooled cell
#define WS_NEEDED_BYTES ((size_t)(WS_POOL + (size_t)BATCH * CC * 128 * 2) * 4)

// ---------------- Pass 1: conv + batch stats (+ pooled max/min store) ----------------
template<bool STORE>
__global__ __launch_bounds__(128) void pass1_kernel(
    const float* __restrict__ x1, const float* __restrict__ x2,
    const float* __restrict__ conv_w, const float* __restrict__ conv_b,
    float* __restrict__ ws)
{
    __shared__ float lds[2][19 * 20];   // stride 20 to avoid bank conflicts

    int blk = blockIdx.x;               // blk = b*64 + c
    int c = blk & 63;
    int t = threadIdx.x;

    const float* src1 = x1 + (size_t)blk * 361;
    const float* src2 = x2 + (size_t)blk * 361;
    for (int i = t; i < 361; i += 128) {
        int r = i / 19;
        int col = i - r * 19;
        lds[0][r * 20 + col] = src1[i];
        lds[1][r * 20 + col] = src2[i];
    }

    int o = t >> 6;       // wave-uniform output channel
    int l = t & 63;
    int pi = l >> 3, pj = l & 7;

    const float* wcp = conv_w + c * 36 + o * 18;
    float w0[9], w1[9];
    #pragma unroll
    for (int k = 0; k < 9; k++) { w0[k] = wcp[k]; w1[k] = wcp[9 + k]; }
    float cbv = conv_b[c * 2 + o];

    __syncthreads();

    // 4x4 input window per ic -> 4 conv outputs (one pooled cell)
    float xw[2][4][4];
    int base = (2 * pi) * 20 + 2 * pj;
    #pragma unroll
    for (int ic = 0; ic < 2; ic++)
        #pragma unroll
        for (int r = 0; r < 4; r++)
            #pragma unroll
            for (int cc = 0; cc < 4; cc++)
                xw[ic][r][cc] = lds[ic][base + r * 20 + cc];

    float s = 0.f, q = 0.f, mx = -3.4e38f, mn = 3.4e38f;
    #pragma unroll
    for (int di = 0; di < 2; di++)
        #pragma unroll
        for (int dj = 0; dj < 2; dj++) {
            float acc = cbv;
            #pragma unroll
            for (int ki = 0; ki < 3; ki++)
                #pragma unroll
                for (int kj = 0; kj < 3; kj++) {
                    acc = fmaf(xw[0][di + ki][dj + kj], w0[ki * 3 + kj], acc);
                    acc = fmaf(xw[1][di + ki][dj + kj], w1[ki * 3 + kj], acc);
                }
            s += acc; q = fmaf(acc, acc, q);
            mx = fmaxf(mx, acc); mn = fminf(mn, acc);
        }

    if (STORE) {
        float2* pool = (float2*)(ws + WS_POOL);
        pool[(size_t)blk * 128 + t] = make_float2(mx, mn);
    }

    // border outputs (stats only): (16, 0..16) and (0..15, 16) -> 33 per o
    if (l < 33) {
        int bi = l < 17 ? 16 : l - 17;
        int bj = l < 17 ? l : 16;
        float acc = cbv;
        int bb = bi * 20 + bj;
        #pragma unroll
        for (int ki = 0; ki < 3; ki++)
            #pragma unroll
            for (int kj = 0; kj < 3; kj++) {
                acc = fmaf(lds[0][bb + ki * 20 + kj], w0[ki * 3 + kj], acc);
                acc = fmaf(lds[1][bb + ki * 20 + kj], w1[ki * 3 + kj], acc);
            }
        s += acc; q = fmaf(acc, acc, q);
    }

    #pragma unroll
    for (int off = 32; off > 0; off >>= 1) {
        s += __shfl_down(s, off);
        q += __shfl_down(q, off);
    }
    if (l == 0) {
        int rep = blk & 31;
        atomicAdd(&ws[WS_SUMR + rep * 128 + c * 2 + o], s);
        atomicAdd(&ws[WS_SQR  + rep * 128 + c * 2 + o], q);
    }
}

// ---------------- Prep: replica-sum stats, BN scale/shift, folded fc weights ----------------
__global__ __launch_bounds__(128) void prep_kernel(
    const float* __restrict__ bn_g, const float* __restrict__ bn_b,
    const float* __restrict__ fc1_w, const float* __restrict__ fc1_b,
    const float* __restrict__ fc2_w, const float* __restrict__ fc2_b,
    const float* __restrict__ w_out,
    float* __restrict__ ws)
{
    int c = blockIdx.x;
    int f = threadIdx.x;

    float wsum = 0.f;
    #pragma unroll
    for (int h = 0; h < 8; h++)
        wsum += fc2_w[c * 8 + h] * fc1_w[(c * 8 + h) * 128 + f];
    ws[WS_WF + c * 128 + f] = w_out[c] * wsum;

    if (f == 0) {
        float bsum = fc2_b[c];
        #pragma unroll
        for (int h = 0; h < 8; h++)
            bsum += fc2_w[c * 8 + h] * fc1_b[c * 8 + h];
        ws[WS_WB + c] = w_out[c] * bsum;
    }
    if (f < 2) {
        int idx = c * 2 + f;
        float s = 0.f, q = 0.f;
        for (int r = 0; r < 32; r++) {
            s += ws[WS_SUMR + r * 128 + idx];
            q += ws[WS_SQR  + r * 128 + idx];
        }
        const float N = 2048.0f * 289.0f;
        float mean = s / N;
        float var  = q / N - mean * mean;
        float inv  = rsqrtf(var + EPS);
        float A    = bn_g[idx] * inv;
        ws[WS_A + idx] = A;
        ws[WS_B + idx] = bn_b[idx] - mean * A;
    }
}

// ---------------- Pass 2 (pool path): stream pooled max/min -> logits -> sigmoid ----------------
__global__ __launch_bounds__(256) void pass2_kernel(
    const float* __restrict__ ws, const float* __restrict__ b_out,
    float* __restrict__ out)
{
    __shared__ float red[4];
    int b = blockIdx.x;
    int t = threadIdx.x;
    const float2* pool = (const float2*)(ws + WS_POOL);

    float partial = (t < 64) ? ws[WS_WB + t] : 0.f;
    if (t == 0) partial += b_out[0];

    #pragma unroll
    for (int i = 0; i < 32; i++) {
        int k = t + i * 256;
        float2 p = pool[(size_t)b * 8192 + k];
        float A  = ws[WS_A + (k >> 6)];   // wave-uniform -> scalar load
        float Bs = ws[WS_B + (k >> 6)];
        float val = A > 0.f ? p.x : p.y;
        float v = fmaf(A, val, Bs);
        v = v > 0.f ? v : SLOPE * v;
        partial = fmaf(v, ws[WS_WF + k], partial);
    }

    #pragma unroll
    for (int off = 32; off > 0; off >>= 1)
        partial += __shfl_down(partial, off);
    if ((t & 63) == 0) red[t >> 6] = partial;
    __syncthreads();
    if (t == 0) {
        float lsum = red[0] + red[1] + red[2] + red[3];
        out[b] = 1.f / (1.f + expf(-lsum));
    }
}

// ---------------- Fallback path: recompute conv with BN applied ----------------
__global__ __launch_bounds__(128) void main_fb_kernel(
    const float* __restrict__ x1, const float* __restrict__ x2,
    const float* __restrict__ conv_w, const float* __restrict__ conv_b,
    float* __restrict__ ws)
{
    __shared__ float lds[2][19 * 20];
    __shared__ float red[2];

    int blk = blockIdx.x;
    int c = blk & 63;
    int b = blk >> 6;
    int t = threadIdx.x;

    const float* src1 = x1 + (size_t)blk * 361;
    const float* src2 = x2 + (size_t)blk * 361;
    for (int i = t; i < 361; i += 128) {
        int r = i / 19;
        int col = i - r * 19;
        lds[0][r * 20 + col] = src1[i];
        lds[1][r * 20 + col] = src2[i];
    }

    int o = t >> 6;
    int l = t & 63;
    int pi = l >> 3, pj = l & 7;

    const float* wcp = conv_w + c * 36 + o * 18;
    float w0[9], w1[9];
    #pragma unroll
    for (int k = 0; k < 9; k++) { w0[k] = wcp[k]; w1[k] = wcp[9 + k]; }
    float cbv = conv_b[c * 2 + o];
    float A   = ws[WS_A + c * 2 + o];
    float Bs  = ws[WS_B + c * 2 + o];
    float wf  = ws[WS_WF + c * 128 + t];

    __syncthreads();

    float xw[2][4][4];
    int base = (2 * pi) * 20 + 2 * pj;
    #pragma unroll
    for (int ic = 0; ic < 2; ic++)
        #pragma unroll
        for (int r = 0; r < 4; r++)
            #pragma unroll
            for (int cc = 0; cc < 4; cc++)
                xw[ic][r][cc] = lds[ic][base + r * 20 + cc];

    float m = -3.4e38f;
    #pragma unroll
    for (int di = 0; di < 2; di++)
        #pragma unroll
        for (int dj = 0; dj < 2; dj++) {
            float acc = cbv;
            #pragma unroll
            for (int ki = 0; ki < 3; ki++)
                #pragma unroll
                for (int kj = 0; kj < 3; kj++) {
                    acc = fmaf(xw[0][di + ki][dj + kj], w0[ki * 3 + kj], acc);
                    acc = fmaf(xw[1][di + ki][dj + kj], w1[ki * 3 + kj], acc);
                }
            float v = fmaf(A, acc, Bs);
            v = v > 0.f ? v : SLOPE * v;
            m = fmaxf(m, v);
        }

    float contrib = m * wf;
    #pragma unroll
    for (int off = 32; off > 0; off >>= 1)
        contrib += __shfl_down(contrib, off);
    if (l == 0) red[o] = contrib;
    __syncthreads();
    if (t == 0)
        atomicAdd(&ws[WS_LOGIT + b], red[0] + red[1]);
}

__global__ __launch_bounds__(256) void final_fb_kernel(
    const float* __restrict__ ws, const float* __restrict__ b_out,
    float* __restrict__ out)
{
    int b = blockIdx.x * blockDim.x + threadIdx.x;
    if (b >= BATCH) return;
    float bias = b_out[0];
    #pragma unroll
    for (int c = 0; c < CC; c++) bias += ws[WS_WB + c];
    float l = ws[WS_LOGIT + b] + bias;
    out[b] = 1.f / (1.f + expf(-l));
}

extern "C" void kernel_launch(void* const* d_in, const int* in_sizes, int n_in,
                              void* d_out, int out_size, void* d_ws, size_t ws_size,
                              hipStream_t stream) {
    const float* x1     = (const float*)d_in[0];
    const float* x2     = (const float*)d_in[1];
    const float* conv_w = (const float*)d_in[2];
    const float* conv_b = (const float*)d_in[3];
    const float* bn_g   = (const float*)d_in[4];
    const float* bn_b   = (const float*)d_in[5];
    const float* fc1_w  = (const float*)d_in[6];
    const float* fc1_b  = (const float*)d_in[7];
    const float* fc2_w  = (const float*)d_in[8];
    const float* fc2_b  = (const float*)d_in[9];
    const float* w_out  = (const float*)d_in[10];
    const float* b_out  = (const float*)d_in[11];
    float* ws  = (float*)d_ws;
    float* out = (float*)d_out;

    // zero stats replicas + fallback logits (A/B/WF overwritten by prep)
    hipMemsetAsync(d_ws, 0, 18752 * sizeof(float), stream);

    dim3 big(BATCH * CC);
    bool pool_path = ws_size >= WS_NEEDED_BYTES;

    if (pool_path) {
        pass1_kernel<true><<<big, 128, 0, stream>>>(x1, x2, conv_w, conv_b, ws);
        prep_kernel<<<CC, 128, 0, stream>>>(bn_g, bn_b, fc1_w, fc1_b, fc2_w, fc2_b, w_out, ws);
        pass2_kernel<<<BATCH, 256, 0, stream>>>(ws, b_out, out);
    } else {
        pass1_kernel<false><<<big, 128, 0, stream>>>(x1, x2, conv_w, conv_b, ws);
        prep_kernel<<<CC, 128, 0, stream>>>(bn_g, bn_b, fc1_w, fc1_b, fc2_w, fc2_b, w_out, ws);
        main_fb_kernel<<<big, 128, 0, stream>>>(x1, x2, conv_w, conv_b, ws);
        final_fb_kernel<<<(BATCH + 255) / 256, 256, 0, stream>>>(ws, b_out, out);
    }
}

// Round 4
// 183.739 us; speedup vs baseline: 5.6135x; 1.0147x over previous
//
#include <hip/hip_runtime.h>
#include <math.h>

#define CC    64
#define BATCH 2048
#define EPS   1e-5f
#define SLOPE 0.01f

// ws layout (float indices):
#define WS_SUMR  0        // 32 replicas x 128 (c,o)
#define WS_SQR   4096     // 32 replicas x 128
#define WS_A     8192     // 128
#define WS_B     8320     // 128
#define WS_WF    8448     // 64*128 folded weights
#define WS_WB    16640    // 64 per-channel bias contribution
#define WS_LOGIT 16704    // 2048 (fallback path only)
#define WS_POOL  18944    // 2048*64*128 uint (bf16 mx | bf16 mn), 16B-aligned
#define WS_NEEDED_BYTES ((size_t)(WS_POOL + (size_t)BATCH * CC * 128) * 4)

__device__ inline unsigned bf16rne(float x) {
    unsigned u = __float_as_uint(x);
    return (u + 0x7fffu + ((u >> 16) & 1u)) >> 16;
}

// ---------------- Pass 1: conv + batch stats (+ pooled bf16 max/min store) ----------------
template<bool STORE>
__global__ __launch_bounds__(128, 7) void pass1_kernel(
    const float* __restrict__ x1, const float* __restrict__ x2,
    const float* __restrict__ conv_w, const float* __restrict__ conv_b,
    float* __restrict__ ws)
{
    __shared__ float lds[2][19 * 20];   // row stride 20 floats (even -> float2 aligned)

    int blk = blockIdx.x;               // blk = b*64 + c
    int c = blk & 63;
    int t = threadIdx.x;

    const float* src1 = x1 + (size_t)blk * 361;
    const float* src2 = x2 + (size_t)blk * 361;
    #pragma unroll
    for (int it = 0; it < 3; it++) {
        int i = t + it * 128;
        if (i < 361) {
            int r = i / 19;
            int col = i - r * 19;
            lds[0][r * 20 + col] = src1[i];
            lds[1][r * 20 + col] = src2[i];
        }
    }

    int o = t >> 6;       // wave-uniform output channel
    int l = t & 63;
    int pi = l >> 3, pj = l & 7;

    const float* wcp = conv_w + c * 36 + o * 18;
    float w0[9], w1[9];
    #pragma unroll
    for (int k = 0; k < 9; k++) { w0[k] = wcp[k]; w1[k] = wcp[9 + k]; }
    float cbv = conv_b[c * 2 + o];

    __syncthreads();

    // rolling-row conv: 4 outputs (2x2 pool window), rows streamed as float2 pairs
    float a00 = cbv, a01 = cbv, a10 = cbv, a11 = cbv;
    {
        const float2* l0 = (const float2*)&lds[0][0];
        const float2* l1 = (const float2*)&lds[1][0];
        #pragma unroll
        for (int r = 0; r < 4; r++) {
            int fo = (2 * pi + r) * 10 + pj;
            float2 p0 = l0[fo], p1 = l0[fo + 1];
            float2 q0 = l1[fo], q1 = l1[fo + 1];
            float xr0[4] = { p0.x, p0.y, p1.x, p1.y };
            float xr1[4] = { q0.x, q0.y, q1.x, q1.y };
            #pragma unroll
            for (int di = 0; di < 2; di++) {
                int ki = r - di;
                if (ki < 0 || ki > 2) continue;
                #pragma unroll
                for (int dj = 0; dj < 2; dj++) {
                    float acc = (di == 0) ? (dj == 0 ? a00 : a01) : (dj == 0 ? a10 : a11);
                    #pragma unroll
                    for (int kj = 0; kj < 3; kj++) {
                        acc = fmaf(xr0[dj + kj], w0[ki * 3 + kj], acc);
                        acc = fmaf(xr1[dj + kj], w1[ki * 3 + kj], acc);
                    }
                    if (di == 0) { if (dj == 0) a00 = acc; else a01 = acc; }
                    else         { if (dj == 0) a10 = acc; else a11 = acc; }
                }
            }
        }
    }

    float s = a00 + a01 + a10 + a11;
    float q = fmaf(a00, a00, fmaf(a01, a01, fmaf(a10, a10, a11 * a11)));
    float mx = fmaxf(fmaxf(a00, a01), fmaxf(a10, a11));
    float mn = fminf(fminf(a00, a01), fminf(a10, a11));

    if (STORE) {
        unsigned* pool = (unsigned*)(ws + WS_POOL);
        pool[(size_t)blk * 128 + t] = (bf16rne(mx) << 16) | bf16rne(mn);
    }

    // border outputs (stats only): (16, 0..16) and (0..15, 16) -> 33 per o
    if (l < 33) {
        int bi = l < 17 ? 16 : l - 17;
        int bj = l < 17 ? l : 16;
        float acc = cbv;
        int bb = bi * 20 + bj;
        #pragma unroll
        for (int ki = 0; ki < 3; ki++)
            #pragma unroll
            for (int kj = 0; kj < 3; kj++) {
                acc = fmaf(lds[0][bb + ki * 20 + kj], w0[ki * 3 + kj], acc);
                acc = fmaf(lds[1][bb + ki * 20 + kj], w1[ki * 3 + kj], acc);
            }
        s += acc; q = fmaf(acc, acc, q);
    }

    #pragma unroll
    for (int off = 32; off > 0; off >>= 1) {
        s += __shfl_down(s, off);
        q += __shfl_down(q, off);
    }
    if (l == 0) {
        int rep = blk & 31;
        atomicAdd(&ws[WS_SUMR + rep * 128 + c * 2 + o], s);
        atomicAdd(&ws[WS_SQR  + rep * 128 + c * 2 + o], q);
    }
}

// ---------------- Prep: replica-sum stats, BN scale/shift, folded fc weights ----------------
__global__ __launch_bounds__(128) void prep_kernel(
    const float* __restrict__ bn_g, const float* __restrict__ bn_b,
    const float* __restrict__ fc1_w, const float* __restrict__ fc1_b,
    const float* __restrict__ fc2_w, const float* __restrict__ fc2_b,
    const float* __restrict__ w_out,
    float* __restrict__ ws)
{
    int c = blockIdx.x;
    int f = threadIdx.x;

    float wsum = 0.f;
    #pragma unroll
    for (int h = 0; h < 8; h++)
        wsum += fc2_w[c * 8 + h] * fc1_w[(c * 8 + h) * 128 + f];
    ws[WS_WF + c * 128 + f] = w_out[c] * wsum;

    if (f == 0) {
        float bsum = fc2_b[c];
        #pragma unroll
        for (int h = 0; h < 8; h++)
            bsum += fc2_w[c * 8 + h] * fc1_b[c * 8 + h];
        ws[WS_WB + c] = w_out[c] * bsum;
    }
    if (f < 2) {
        int idx = c * 2 + f;
        float s = 0.f, q = 0.f;
        for (int r = 0; r < 32; r++) {
            s += ws[WS_SUMR + r * 128 + idx];
            q += ws[WS_SQR  + r * 128 + idx];
        }
        const float N = 2048.0f * 289.0f;
        float mean = s / N;
        float var  = q / N - mean * mean;
        float inv  = rsqrtf(var + EPS);
        float A    = bn_g[idx] * inv;
        ws[WS_A + idx] = A;
        ws[WS_B + idx] = bn_b[idx] - mean * A;
    }
}

// ---------------- Pass 2: stream bf16 pool -> logits -> sigmoid ----------------
__global__ __launch_bounds__(256) void pass2_kernel(
    const float* __restrict__ ws, const float* __restrict__ b_out,
    float* __restrict__ out)
{
    __shared__ float red[4];
    int b = blockIdx.x;
    int t = threadIdx.x;
    const uint4* pool = (const uint4*)(ws + WS_POOL) + (size_t)b * 2048;

    float partial = (t < 64) ? ws[WS_WB + t] : 0.f;
    if (t == 0) partial += b_out[0];

    #pragma unroll
    for (int i = 0; i < 8; i++) {
        uint4 p = pool[t + i * 256];
        int k0 = (t + i * 256) * 4;
        float A  = ws[WS_A + (k0 >> 6)];
        float Bs = ws[WS_B + (k0 >> 6)];
        const float4 wf = *(const float4*)&ws[WS_WF + k0];
        unsigned uu[4] = { p.x, p.y, p.z, p.w };
        float wfv[4] = { wf.x, wf.y, wf.z, wf.w };
        #pragma unroll
        for (int j = 0; j < 4; j++) {
            float mx = __uint_as_float(uu[j] & 0xffff0000u);
            float mn = __uint_as_float(uu[j] << 16);
            float val = A > 0.f ? mx : mn;
            float v = fmaf(A, val, Bs);
            v = v > 0.f ? v : SLOPE * v;
            partial = fmaf(v, wfv[j], partial);
        }
    }

    #pragma unroll
    for (int off = 32; off > 0; off >>= 1)
        partial += __shfl_down(partial, off);
    if ((t & 63) == 0) red[t >> 6] = partial;
    __syncthreads();
    if (t == 0) {
        float lsum = red[0] + red[1] + red[2] + red[3];
        out[b] = 1.f / (1.f + expf(-lsum));
    }
}

// ---------------- Fallback path (small ws): recompute conv with BN applied ----------------
__global__ __launch_bounds__(128) void main_fb_kernel(
    const float* __restrict__ x1, const float* __restrict__ x2,
    const float* __restrict__ conv_w, const float* __restrict__ conv_b,
    float* __restrict__ ws)
{
    __shared__ float lds[2][19 * 20];
    __shared__ float red[2];

    int blk = blockIdx.x;
    int c = blk & 63;
    int b = blk >> 6;
    int t = threadIdx.x;

    const float* src1 = x1 + (size_t)blk * 361;
    const float* src2 = x2 + (size_t)blk * 361;
    for (int i = t; i < 361; i += 128) {
        int r = i / 19;
        int col = i - r * 19;
        lds[0][r * 20 + col] = src1[i];
        lds[1][r * 20 + col] = src2[i];
    }

    int o = t >> 6;
    int l = t & 63;
    int pi = l >> 3, pj = l & 7;

    const float* wcp = conv_w + c * 36 + o * 18;
    float w0[9], w1[9];
    #pragma unroll
    for (int k = 0; k < 9; k++) { w0[k] = wcp[k]; w1[k] = wcp[9 + k]; }
    float cbv = conv_b[c * 2 + o];
    float A   = ws[WS_A + c * 2 + o];
    float Bs  = ws[WS_B + c * 2 + o];
    float wf  = ws[WS_WF + c * 128 + t];

    __syncthreads();

    float xw[2][4][4];
    int base = (2 * pi) * 20 + 2 * pj;
    #pragma unroll
    for (int ic = 0; ic < 2; ic++)
        #pragma unroll
        for (int r = 0; r < 4; r++)
            #pragma unroll
            for (int cc = 0; cc < 4; cc++)
                xw[ic][r][cc] = lds[ic][base + r * 20 + cc];

    float m = -3.4e38f;
    #pragma unroll
    for (int di = 0; di < 2; di++)
        #pragma unroll
        for (int dj = 0; dj < 2; dj++) {
            float acc = cbv;
            #pragma unroll
            for (int ki = 0; ki < 3; ki++)
                #pragma unroll
                for (int kj = 0; kj < 3; kj++) {
                    acc = fmaf(xw[0][di + ki][dj + kj], w0[ki * 3 + kj], acc);
                    acc = fmaf(xw[1][di + ki][dj + kj], w1[ki * 3 + kj], acc);
                }
            float v = fmaf(A, acc, Bs);
            v = v > 0.f ? v : SLOPE * v;
            m = fmaxf(m, v);
        }

    float contrib = m * wf;
    #pragma unroll
    for (int off = 32; off > 0; off >>= 1)
        contrib += __shfl_down(contrib, off);
    if (l == 0) red[o] = contrib;
    __syncthreads();
    if (t == 0)
        atomicAdd(&ws[WS_LOGIT + b], red[0] + red[1]);
}

__global__ __launch_bounds__(256) void final_fb_kernel(
    const float* __restrict__ ws, const float* __restrict__ b_out,
    float* __restrict__ out)
{
    int b = blockIdx.x * blockDim.x + threadIdx.x;
    if (b >= BATCH) return;
    float bias = b_out[0];
    #pragma unroll
    for (int c = 0; c < CC; c++) bias += ws[WS_WB + c];
    float l = ws[WS_LOGIT + b] + bias;
    out[b] = 1.f / (1.f + expf(-l));
}

extern "C" void kernel_launch(void* const* d_in, const int* in_sizes, int n_in,
                              void* d_out, int out_size, void* d_ws, size_t ws_size,
                              hipStream_t stream) {
    const float* x1     = (const float*)d_in[0];
    const float* x2     = (const float*)d_in[1];
    const float* conv_w = (const float*)d_in[2];
    const float* conv_b = (const float*)d_in[3];
    const float* bn_g   = (const float*)d_in[4];
    const float* bn_b   = (const float*)d_in[5];
    const float* fc1_w  = (const float*)d_in[6];
    const float* fc1_b  = (const float*)d_in[7];
    const float* fc2_w  = (const float*)d_in[8];
    const float* fc2_b  = (const float*)d_in[9];
    const float* w_out  = (const float*)d_in[10];
    const float* b_out  = (const float*)d_in[11];
    float* ws  = (float*)d_ws;
    float* out = (float*)d_out;

    dim3 big(BATCH * CC);
    bool pool_path = ws_size >= WS_NEEDED_BYTES;

    if (pool_path) {
        hipMemsetAsync(d_ws, 0, 8192 * sizeof(float), stream);   // stats replicas
        pass1_kernel<true><<<big, 128, 0, stream>>>(x1, x2, conv_w, conv_b, ws);
        prep_kernel<<<CC, 128, 0, stream>>>(bn_g, bn_b, fc1_w, fc1_b, fc2_w, fc2_b, w_out, ws);
        pass2_kernel<<<BATCH, 256, 0, stream>>>(ws, b_out, out);
    } else {
        hipMemsetAsync(d_ws, 0, 18752 * sizeof(float), stream);  // stats + logits
        pass1_kernel<false><<<big, 128, 0, stream>>>(x1, x2, conv_w, conv_b, ws);
        prep_kernel<<<CC, 128, 0, stream>>>(bn_g, bn_b, fc1_w, fc1_b, fc2_w, fc2_b, w_out, ws);
        main_fb_kernel<<<big, 128, 0, stream>>>(x1, x2, conv_w, conv_b, ws);
        final_fb_kernel<<<(BATCH + 255) / 256, 256, 0, stream>>>(ws, b_out, out);
    }
}

// Round 5
// 166.836 us; speedup vs baseline: 6.1822x; 1.1013x over previous
//
#include <hip/hip_runtime.h>
#include <math.h>

#define CC    64
#define BATCH 2048
#define EPS   1e-5f
#define SLOPE 0.01f

// ws layout (float indices):
#define WS_SUMR  0        // 32 replicas x 128 (c,o)
#define WS_SQR   4096     // 32 replicas x 128
#define WS_A     8192     // 128
#define WS_B     8320     // 128
#define WS_WF    8448     // 64*128 folded weights
#define WS_WB    16640    // 64 per-channel bias contribution
#define WS_LOGIT 16704    // 2048 (fallback path only)
#define WS_POOL  18944    // 2048*64*128 uint (bf16 mx | bf16 mn), 16B-aligned
#define WS_NEEDED_BYTES ((size_t)(WS_POOL + (size_t)BATCH * CC * 128) * 4)

__device__ inline unsigned bf16rne(float x) {
    unsigned u = __float_as_uint(x);
    return (u + 0x7fffu + ((u >> 16) & 1u)) >> 16;
}

__device__ inline float2 pk_fma(float2 a, float w, float2 c) {
    return make_float2(fmaf(a.x, w, c.x), fmaf(a.y, w, c.y));
}

// ---------------- Pass 1: conv + batch stats (+ pooled bf16 max/min store) ----------------
// One 128-thread block = 2 images (b, c0) and (b, c0+1); one wave per image.
// LDS layout per image: [ic][parity][19 rows][10] (de-interleaved columns).
// Lane l: o = l>>5, p = l&31, pi = p>>2, pjp = p&3 -> 2 pooled cells (pi, 2pjp), (pi, 2pjp+1).
template<bool STORE>
__global__ __launch_bounds__(128, 4) void pass1_kernel(
    const float* __restrict__ x1, const float* __restrict__ x2,
    const float* __restrict__ conv_w, const float* __restrict__ conv_b,
    float* __restrict__ ws)
{
    __shared__ float lds[2 * 760];   // 2 images x (2 ic x 2 par x 19 x 10)

    int blk = blockIdx.x;            // 2048 * 32
    int b  = blk >> 5;
    int c0 = (blk & 31) * 2;
    int t  = threadIdx.x;

    // staging: 1444 floats (722 from x1 for c0,c0+1 contiguous; 722 from x2)
    const float* bx1 = x1 + ((size_t)b * 64 + c0) * 361;
    const float* bx2 = x2 + ((size_t)b * 64 + c0) * 361;
    #pragma unroll
    for (int it = 0; it < 12; it++) {
        int g = t + it * 128;
        if (g < 1444) {
            int icx = g >= 722;
            int gg  = icx ? g - 722 : g;
            int img = gg >= 361;
            int j   = img ? gg - 361 : gg;
            int row = j / 19;
            int col = j - row * 19;
            float v = icx ? bx2[gg] : bx1[gg];
            lds[img * 760 + icx * 380 + (col & 1) * 190 + row * 10 + (col >> 1)] = v;
        }
    }

    int wv  = t >> 6;               // image index within block (wave id)
    int l   = t & 63;
    int o   = l >> 5;               // output channel (half-wave)
    int p   = l & 31;
    int pi  = p >> 2;
    int pjp = p & 3;
    int c   = c0 + wv;

    // weights: conv_w[c][o][ic][ki][kj]; per-lane load (2 distinct addrs/wave -> L1 broadcast)
    const float* wp = conv_w + (size_t)(c * 2 + o) * 18;
    float wgt[18];
    #pragma unroll
    for (int k = 0; k < 18; k++) wgt[k] = wp[k];
    float cbv = conv_b[c * 2 + o];

    __syncthreads();

    // 8 outputs as float2: acc2[di*2+dj] = {cellA, cellB}
    float2 acc2[4];
    #pragma unroll
    for (int i = 0; i < 4; i++) acc2[i] = make_float2(cbv, cbv);

    const float2* L2 = (const float2*)lds;
    int ibase = wv * 760;

    #pragma unroll
    for (int ic = 0; ic < 2; ic++) {
        const float* w = &wgt[ic * 9];
        #pragma unroll
        for (int r = 0; r < 4; r++) {
            int row = 2 * pi + r;
            int ebase = ibase + ic * 380 + row * 10 + 2 * pjp;   // even plane
            int obase = ebase + 190;                             // odd plane
            float2 p0 = L2[ebase >> 1];          // {c0, c2}
            float2 p1 = L2[obase >> 1];          // {c1, c3}
            float  e2 = lds[ebase + 2];          // c4
            float  o2 = lds[obase + 2];          // c5
            float2 xp[4] = { p0, p1, make_float2(p0.y, e2), make_float2(p1.y, o2) };
            #pragma unroll
            for (int di = 0; di < 2; di++) {
                int ki = r - di;
                if (ki < 0 || ki > 2) continue;
                #pragma unroll
                for (int dj = 0; dj < 2; dj++) {
                    #pragma unroll
                    for (int kj = 0; kj < 3; kj++)
                        acc2[di * 2 + dj] = pk_fma(xp[dj + kj], w[ki * 3 + kj], acc2[di * 2 + dj]);
                }
            }
        }
    }

    float2 s2 = make_float2(0.f, 0.f), q2 = make_float2(0.f, 0.f);
    float mxA = -3.4e38f, mnA = 3.4e38f, mxB = -3.4e38f, mnB = 3.4e38f;
    #pragma unroll
    for (int i = 0; i < 4; i++) {
        s2.x += acc2[i].x; s2.y += acc2[i].y;
        q2 = pk_fma(acc2[i], 0.f, q2), q2 = make_float2(fmaf(acc2[i].x, acc2[i].x, q2.x),
                                                        fmaf(acc2[i].y, acc2[i].y, q2.y));
        mxA = fmaxf(mxA, acc2[i].x); mnA = fminf(mnA, acc2[i].x);
        mxB = fmaxf(mxB, acc2[i].y); mnB = fminf(mnB, acc2[i].y);
    }
    float s = s2.x + s2.y;
    float q = q2.x + q2.y;

    if (STORE) {
        unsigned* pool = (unsigned*)(ws + WS_POOL);
        size_t pix = ((size_t)(b * 64 + c)) * 128 + o * 64 + pi * 8 + 2 * pjp;
        uint2 pk;
        pk.x = (bf16rne(mxA) << 16) | bf16rne(mnA);
        pk.y = (bf16rne(mxB) << 16) | bf16rne(mnB);
        *(uint2*)&pool[pix] = pk;
    }

    // border outputs (stats only): 33 per o: (16, 0..16) and (0..15, 16)
    #pragma unroll
    for (int rep = 0; rep < 2; rep++) {
        int bidx = p + rep * 32;
        if (bidx < 33) {
            int bi = bidx < 17 ? 16 : bidx - 17;
            int bj = bidx < 17 ? bidx : 16;
            float accb = cbv;
            #pragma unroll
            for (int ic = 0; ic < 2; ic++)
                #pragma unroll
                for (int ki = 0; ki < 3; ki++)
                    #pragma unroll
                    for (int kj = 0; kj < 3; kj++) {
                        int col = bj + kj;
                        float v = lds[ibase + ic * 380 + (col & 1) * 190 + (bi + ki) * 10 + (col >> 1)];
                        accb = fmaf(v, wgt[ic * 9 + ki * 3 + kj], accb);
                    }
            s += accb; q = fmaf(accb, accb, q);
        }
    }

    // reduce within each 32-lane half
    #pragma unroll
    for (int off = 16; off > 0; off >>= 1) {
        s += __shfl_down(s, off, 32);
        q += __shfl_down(q, off, 32);
    }
    if (p == 0) {
        int rep = blk & 31;
        atomicAdd(&ws[WS_SUMR + rep * 128 + c * 2 + o], s);
        atomicAdd(&ws[WS_SQR  + rep * 128 + c * 2 + o], q);
    }
}

// ---------------- Prep: replica-sum stats, BN scale/shift, folded fc weights ----------------
__global__ __launch_bounds__(128) void prep_kernel(
    const float* __restrict__ bn_g, const float* __restrict__ bn_b,
    const float* __restrict__ fc1_w, const float* __restrict__ fc1_b,
    const float* __restrict__ fc2_w, const float* __restrict__ fc2_b,
    const float* __restrict__ w_out,
    float* __restrict__ ws)
{
    int c = blockIdx.x;
    int f = threadIdx.x;

    float wsum = 0.f;
    #pragma unroll
    for (int h = 0; h < 8; h++)
        wsum += fc2_w[c * 8 + h] * fc1_w[(c * 8 + h) * 128 + f];
    ws[WS_WF + c * 128 + f] = w_out[c] * wsum;

    if (f == 0) {
        float bsum = fc2_b[c];
        #pragma unroll
        for (int h = 0; h < 8; h++)
            bsum += fc2_w[c * 8 + h] * fc1_b[c * 8 + h];
        ws[WS_WB + c] = w_out[c] * bsum;
    }
    if (f < 2) {
        int idx = c * 2 + f;
        float s = 0.f, q = 0.f;
        for (int r = 0; r < 32; r++) {
            s += ws[WS_SUMR + r * 128 + idx];
            q += ws[WS_SQR  + r * 128 + idx];
        }
        const float N = 2048.0f * 289.0f;
        float mean = s / N;
        float var  = q / N - mean * mean;
        float inv  = rsqrtf(var + EPS);
        float A    = bn_g[idx] * inv;
        ws[WS_A + idx] = A;
        ws[WS_B + idx] = bn_b[idx] - mean * A;
    }
}

// ---------------- Pass 2: stream bf16 pool -> logits -> sigmoid ----------------
__global__ __launch_bounds__(256) void pass2_kernel(
    const float* __restrict__ ws, const float* __restrict__ b_out,
    float* __restrict__ out)
{
    __shared__ float red[4];
    int b = blockIdx.x;
    int t = threadIdx.x;
    const uint4* pool = (const uint4*)(ws + WS_POOL) + (size_t)b * 2048;

    float partial = (t < 64) ? ws[WS_WB + t] : 0.f;
    if (t == 0) partial += b_out[0];

    #pragma unroll
    for (int i = 0; i < 8; i++) {
        uint4 p = pool[t + i * 256];
        int k0 = (t + i * 256) * 4;
        float A  = ws[WS_A + (k0 >> 6)];
        float Bs = ws[WS_B + (k0 >> 6)];
        const float4 wf = *(const float4*)&ws[WS_WF + k0];
        unsigned uu[4] = { p.x, p.y, p.z, p.w };
        float wfv[4] = { wf.x, wf.y, wf.z, wf.w };
        #pragma unroll
        for (int j = 0; j < 4; j++) {
            float mx = __uint_as_float(uu[j] & 0xffff0000u);
            float mn = __uint_as_float(uu[j] << 16);
            float val = A > 0.f ? mx : mn;
            float v = fmaf(A, val, Bs);
            v = v > 0.f ? v : SLOPE * v;
            partial = fmaf(v, wfv[j], partial);
        }
    }

    #pragma unroll
    for (int off = 32; off > 0; off >>= 1)
        partial += __shfl_down(partial, off);
    if ((t & 63) == 0) red[t >> 6] = partial;
    __syncthreads();
    if (t == 0) {
        float lsum = red[0] + red[1] + red[2] + red[3];
        out[b] = 1.f / (1.f + expf(-lsum));
    }
}

// ---------------- Fallback path (small ws): recompute conv with BN applied ----------------
__global__ __launch_bounds__(128) void main_fb_kernel(
    const float* __restrict__ x1, const float* __restrict__ x2,
    const float* __restrict__ conv_w, const float* __restrict__ conv_b,
    float* __restrict__ ws)
{
    __shared__ float lds[2][19 * 20];
    __shared__ float red[2];

    int blk = blockIdx.x;
    int c = blk & 63;
    int b = blk >> 6;
    int t = threadIdx.x;

    const float* src1 = x1 + (size_t)blk * 361;
    const float* src2 = x2 + (size_t)blk * 361;
    for (int i = t; i < 361; i += 128) {
        int r = i / 19;
        int col = i - r * 19;
        lds[0][r * 20 + col] = src1[i];
        lds[1][r * 20 + col] = src2[i];
    }

    int o = t >> 6;
    int l = t & 63;
    int pi = l >> 3, pj = l & 7;

    const float* wcp = conv_w + c * 36 + o * 18;
    float w0[9], w1[9];
    #pragma unroll
    for (int k = 0; k < 9; k++) { w0[k] = wcp[k]; w1[k] = wcp[9 + k]; }
    float cbv = conv_b[c * 2 + o];
    float A   = ws[WS_A + c * 2 + o];
    float Bs  = ws[WS_B + c * 2 + o];
    float wf  = ws[WS_WF + c * 128 + t];

    __syncthreads();

    float xw[2][4][4];
    int base = (2 * pi) * 20 + 2 * pj;
    #pragma unroll
    for (int ic = 0; ic < 2; ic++)
        #pragma unroll
        for (int r = 0; r < 4; r++)
            #pragma unroll
            for (int cc = 0; cc < 4; cc++)
                xw[ic][r][cc] = lds[ic][base + r * 20 + cc];

    float m = -3.4e38f;
    #pragma unroll
    for (int di = 0; di < 2; di++)
        #pragma unroll
        for (int dj = 0; dj < 2; dj++) {
            float acc = cbv;
            #pragma unroll
            for (int ki = 0; ki < 3; ki++)
                #pragma unroll
                for (int kj = 0; kj < 3; kj++) {
                    acc = fmaf(xw[0][di + ki][dj + kj], w0[ki * 3 + kj], acc);
                    acc = fmaf(xw[1][di + ki][dj + kj], w1[ki * 3 + kj], acc);
                }
            float v = fmaf(A, acc, Bs);
            v = v > 0.f ? v : SLOPE * v;
            m = fmaxf(m, v);
        }

    float contrib = m * wf;
    #pragma unroll
    for (int off = 32; off > 0; off >>= 1)
        contrib += __shfl_down(contrib, off);
    if (l == 0) red[o] = contrib;
    __syncthreads();
    if (t == 0)
        atomicAdd(&ws[WS_LOGIT + b], red[0] + red[1]);
}

__global__ __launch_bounds__(256) void final_fb_kernel(
    const float* __restrict__ ws, const float* __restrict__ b_out,
    float* __restrict__ out)
{
    int b = blockIdx.x * blockDim.x + threadIdx.x;
    if (b >= BATCH) return;
    float bias = b_out[0];
    #pragma unroll
    for (int c = 0; c < CC; c++) bias += ws[WS_WB + c];
    float l = ws[WS_LOGIT + b] + bias;
    out[b] = 1.f / (1.f + expf(-l));
}

extern "C" void kernel_launch(void* const* d_in, const int* in_sizes, int n_in,
                              void* d_out, int out_size, void* d_ws, size_t ws_size,
                              hipStream_t stream) {
    const float* x1     = (const float*)d_in[0];
    const float* x2     = (const float*)d_in[1];
    const float* conv_w = (const float*)d_in[2];
    const float* conv_b = (const float*)d_in[3];
    const float* bn_g   = (const float*)d_in[4];
    const float* bn_b   = (const float*)d_in[5];
    const float* fc1_w  = (const float*)d_in[6];
    const float* fc1_b  = (const float*)d_in[7];
    const float* fc2_w  = (const float*)d_in[8];
    const float* fc2_b  = (const float*)d_in[9];
    const float* w_out  = (const float*)d_in[10];
    const float* b_out  = (const float*)d_in[11];
    float* ws  = (float*)d_ws;
    float* out = (float*)d_out;

    dim3 big(BATCH * 32);            // 2 channels per block
    bool pool_path = ws_size >= WS_NEEDED_BYTES;

    if (pool_path) {
        hipMemsetAsync(d_ws, 0, 8192 * sizeof(float), stream);   // stats replicas
        pass1_kernel<true><<<big, 128, 0, stream>>>(x1, x2, conv_w, conv_b, ws);
        prep_kernel<<<CC, 128, 0, stream>>>(bn_g, bn_b, fc1_w, fc1_b, fc2_w, fc2_b, w_out, ws);
        pass2_kernel<<<BATCH, 256, 0, stream>>>(ws, b_out, out);
    } else {
        hipMemsetAsync(d_ws, 0, 18752 * sizeof(float), stream);  // stats + logits
        pass1_kernel<false><<<big, 128, 0, stream>>>(x1, x2, conv_w, conv_b, ws);
        prep_kernel<<<CC, 128, 0, stream>>>(bn_g, bn_b, fc1_w, fc1_b, fc2_w, fc2_b, w_out, ws);
        main_fb_kernel<<<dim3(BATCH * CC), 128, 0, stream>>>(x1, x2, conv_w, conv_b, ws);
        final_fb_kernel<<<(BATCH + 255) / 256, 256, 0, stream>>>(ws, b_out, out);
    }
}

// Round 6
// 151.908 us; speedup vs baseline: 6.7897x; 1.0983x over previous
//
#include <hip/hip_runtime.h>
#include <math.h>

#define CC    64
#define BATCH 2048
#define EPS   1e-5f
#define SLOPE 0.01f

// ws layout (float indices):
#define WS_SUMR  0        // 32 replicas x 128 (c,o)
#define WS_SQR   4096     // 32 replicas x 128
#define WS_A     8192     // 128
#define WS_B     8320     // 128
#define WS_WF    8448     // 64*128 folded weights
#define WS_WB    16640    // 64 per-channel bias contribution
#define WS_LOGIT 16704    // 2048 (fallback path only)
#define WS_POOL  18944    // 2048*64*128 uint (bf16 mx | bf16 mn), 16B-aligned
#define WS_NEEDED_BYTES ((size_t)(WS_POOL + (size_t)BATCH * CC * 128) * 4)

__device__ inline unsigned bf16rne(float x) {
    unsigned u = __float_as_uint(x);
    return (u + 0x7fffu + ((u >> 16) & 1u)) >> 16;
}

// guaranteed packed f32 FMA: acc = a*b + acc (VOP3P v_pk_fma_f32, CDNA4)
__device__ inline void pkfma(float2& acc, float2 a, float2 b) {
    asm("v_pk_fma_f32 %0, %1, %2, %0" : "+v"(acc) : "v"(a), "v"(b));
}

// ---------------- Pass 1: conv + batch stats (+ pooled bf16 max/min store) ----------------
// One 128-thread block = 2 images (b, c0) and (b, c0+1); one wave per image.
// LDS per image: [ic][parity][19 rows][10] (de-interleaved columns).
// Lane l: o = l>>5, p = l&31, pi = p>>2, pjp = p&3 -> cells (pi,2pjp),(pi,2pjp+1).
template<bool STORE>
__global__ __launch_bounds__(128, 4) void pass1_kernel(
    const float* __restrict__ x1, const float* __restrict__ x2,
    const float* __restrict__ conv_w, const float* __restrict__ conv_b,
    float* __restrict__ ws)
{
    __shared__ float lds[2 * 760];   // 2 images x (2 ic x 2 par x 19 x 10)

    int blk = blockIdx.x;            // 2048 * 32
    int b  = blk >> 5;
    int c0 = (blk & 31) * 2;
    int t  = threadIdx.x;

    // staging: 722 float2 per source; bases are 8B-aligned ((64b+c0)*361 even)
    const float2* g1 = (const float2*)(x1 + ((size_t)b * 64 + c0) * 361);
    const float2* g2 = (const float2*)(x2 + ((size_t)b * 64 + c0) * 361);
    #pragma unroll
    for (int icx = 0; icx < 2; icx++) {
        const float2* gs = icx ? g2 : g1;
        #pragma unroll
        for (int it = 0; it < 3; it++) {
            int g = t + it * 128;
            if (g < 361) {
                float2 v = gs[g];
                int e0   = 2 * g;
                int img0 = e0 >= 361;
                int j0   = e0 - 361 * img0;
                int row0 = j0 / 19;
                int col0 = j0 - row0 * 19;
                // e1 = e0+1 incrementally
                int img1 = img0, row1 = row0, col1 = col0 + 1;
                if (col1 == 19) { col1 = 0; row1++; }
                if (row1 == 19) { row1 = 0; img1 = 1; }
                lds[img0 * 760 + icx * 380 + (col0 & 1) * 190 + row0 * 10 + (col0 >> 1)] = v.x;
                lds[img1 * 760 + icx * 380 + (col1 & 1) * 190 + row1 * 10 + (col1 >> 1)] = v.y;
            }
        }
    }

    int wv  = t >> 6;               // image index within block (wave id)
    int l   = t & 63;
    int o   = l >> 5;               // output channel (half-wave)
    int p   = l & 31;
    int pi  = p >> 2;
    int pjp = p & 3;
    int c   = c0 + wv;

    // weights pre-packed as {w,w} pairs
    const float* wp = conv_w + (size_t)(c * 2 + o) * 18;
    float2 wgt[18];
    #pragma unroll
    for (int k = 0; k < 18; k++) { float w = wp[k]; wgt[k] = make_float2(w, w); }
    float cbv = conv_b[c * 2 + o];

    __syncthreads();

    // 8 conv outputs as 4 float2: acc2[di*2+dj] = {cellA(4pjp+dj), cellB(4pjp+2+dj)} at conv row 2pi+di
    float2 acc2[4];
    #pragma unroll
    for (int i = 0; i < 4; i++) acc2[i] = make_float2(cbv, cbv);

    const float2* L2 = (const float2*)lds;
    int ibase = wv * 760;

    #pragma unroll
    for (int ic = 0; ic < 2; ic++) {
        const float2* w = &wgt[ic * 9];
        #pragma unroll
        for (int r = 0; r < 4; r++) {
            int row   = 2 * pi + r;
            int ebase = ibase + ic * 380 + row * 10 + 2 * pjp;   // even plane
            float2 q0 = L2[ebase >> 1];            // {x0, x2}
            float2 q1 = L2[(ebase + 190) >> 1];    // {x1, x3}
            float  e2 = lds[ebase + 2];            // x4
            float  o2 = lds[ebase + 192];          // x5
            float2 q2 = make_float2(q0.y, e2);     // {x2, x4}
            float2 q3 = make_float2(q1.y, o2);     // {x3, x5}
            float2 qq[4] = { q0, q1, q2, q3 };
            #pragma unroll
            for (int di = 0; di < 2; di++) {
                int ki = r - di;
                if (ki < 0 || ki > 2) continue;
                #pragma unroll
                for (int dj = 0; dj < 2; dj++)
                    #pragma unroll
                    for (int kj = 0; kj < 3; kj++)
                        pkfma(acc2[di * 2 + dj], qq[dj + kj], w[ki * 3 + kj]);
            }
        }
    }

    // epilogue: stats + pooled max/min for the two cells
    float2 s2 = make_float2(0.f, 0.f), q2s = make_float2(0.f, 0.f);
    float mxA = -3.4e38f, mnA = 3.4e38f, mxB = -3.4e38f, mnB = 3.4e38f;
    #pragma unroll
    for (int i = 0; i < 4; i++) {
        s2.x += acc2[i].x; s2.y += acc2[i].y;
        pkfma(q2s, acc2[i], acc2[i]);
        mxA = fmaxf(mxA, acc2[i].x); mnA = fminf(mnA, acc2[i].x);
        mxB = fmaxf(mxB, acc2[i].y); mnB = fminf(mnB, acc2[i].y);
    }
    float s = s2.x + s2.y;
    float q = q2s.x + q2s.y;

    if (STORE) {
        unsigned* pool = (unsigned*)(ws + WS_POOL);
        size_t pix = ((size_t)(b * 64 + c)) * 128 + o * 64 + pi * 8 + 2 * pjp;
        uint2 pk;
        pk.x = (bf16rne(mxA) << 16) | bf16rne(mnA);
        pk.y = (bf16rne(mxB) << 16) | bf16rne(mnB);
        *(uint2*)&pool[pix] = pk;
    }

    // border outputs (stats only): 33 per o: (16, 0..16) and (0..15, 16)
    #pragma unroll
    for (int rep = 0; rep < 2; rep++) {
        int bidx = p + rep * 32;
        if (bidx < 33) {
            int bi = bidx < 17 ? 16 : bidx - 17;
            int bj = bidx < 17 ? bidx : 16;
            float accb = cbv;
            #pragma unroll
            for (int ic = 0; ic < 2; ic++)
                #pragma unroll
                for (int ki = 0; ki < 3; ki++)
                    #pragma unroll
                    for (int kj = 0; kj < 3; kj++) {
                        int col = bj + kj;
                        float v = lds[ibase + ic * 380 + (col & 1) * 190 + (bi + ki) * 10 + (col >> 1)];
                        accb = fmaf(v, wgt[ic * 9 + ki * 3 + kj].x, accb);
                    }
            s += accb; q = fmaf(accb, accb, q);
        }
    }

    // reduce within each 32-lane half
    #pragma unroll
    for (int off = 16; off > 0; off >>= 1) {
        s += __shfl_down(s, off, 32);
        q += __shfl_down(q, off, 32);
    }
    if (p == 0) {
        int rep = b & 31;          // b-derived: 64-way spread per (c,o) slot
        atomicAdd(&ws[WS_SUMR + rep * 128 + c * 2 + o], s);
        atomicAdd(&ws[WS_SQR  + rep * 128 + c * 2 + o], q);
    }
}

// ---------------- Prep: replica-sum stats, BN scale/shift, folded fc weights ----------------
__global__ __launch_bounds__(128) void prep_kernel(
    const float* __restrict__ bn_g, const float* __restrict__ bn_b,
    const float* __restrict__ fc1_w, const float* __restrict__ fc1_b,
    const float* __restrict__ fc2_w, const float* __restrict__ fc2_b,
    const float* __restrict__ w_out,
    float* __restrict__ ws)
{
    int c = blockIdx.x;
    int f = threadIdx.x;

    float wsum = 0.f;
    #pragma unroll
    for (int h = 0; h < 8; h++)
        wsum += fc2_w[c * 8 + h] * fc1_w[(c * 8 + h) * 128 + f];
    ws[WS_WF + c * 128 + f] = w_out[c] * wsum;

    if (f == 0) {
        float bsum = fc2_b[c];
        #pragma unroll
        for (int h = 0; h < 8; h++)
            bsum += fc2_w[c * 8 + h] * fc1_b[c * 8 + h];
        ws[WS_WB + c] = w_out[c] * bsum;
    }
    if (f < 2) {
        int idx = c * 2 + f;
        float s = 0.f, q = 0.f;
        for (int r = 0; r < 32; r++) {
            s += ws[WS_SUMR + r * 128 + idx];
            q += ws[WS_SQR  + r * 128 + idx];
        }
        const float N = 2048.0f * 289.0f;
        float mean = s / N;
        float var  = q / N - mean * mean;
        float inv  = rsqrtf(var + EPS);
        float A    = bn_g[idx] * inv;
        ws[WS_A + idx] = A;
        ws[WS_B + idx] = bn_b[idx] - mean * A;
    }
}

// ---------------- Pass 2: stream bf16 pool -> logits -> sigmoid ----------------
__global__ __launch_bounds__(256) void pass2_kernel(
    const float* __restrict__ ws, const float* __restrict__ b_out,
    float* __restrict__ out)
{
    __shared__ float red[4];
    int b = blockIdx.x;
    int t = threadIdx.x;
    const uint4* pool = (const uint4*)(ws + WS_POOL) + (size_t)b * 2048;

    float partial = (t < 64) ? ws[WS_WB + t] : 0.f;
    if (t == 0) partial += b_out[0];

    #pragma unroll
    for (int i = 0; i < 8; i++) {
        uint4 p = pool[t + i * 256];
        int k0 = (t + i * 256) * 4;
        float A  = ws[WS_A + (k0 >> 6)];
        float Bs = ws[WS_B + (k0 >> 6)];
        const float4 wf = *(const float4*)&ws[WS_WF + k0];
        unsigned uu[4] = { p.x, p.y, p.z, p.w };
        float wfv[4] = { wf.x, wf.y, wf.z, wf.w };
        #pragma unroll
        for (int j = 0; j < 4; j++) {
            float mx = __uint_as_float(uu[j] & 0xffff0000u);
            float mn = __uint_as_float(uu[j] << 16);
            float val = A > 0.f ? mx : mn;
            float v = fmaf(A, val, Bs);
            v = v > 0.f ? v : SLOPE * v;
            partial = fmaf(v, wfv[j], partial);
        }
    }

    #pragma unroll
    for (int off = 32; off > 0; off >>= 1)
        partial += __shfl_down(partial, off);
    if ((t & 63) == 0) red[t >> 6] = partial;
    __syncthreads();
    if (t == 0) {
        float lsum = red[0] + red[1] + red[2] + red[3];
        out[b] = 1.f / (1.f + expf(-lsum));
    }
}

// ---------------- Fallback path (small ws): recompute conv with BN applied ----------------
__global__ __launch_bounds__(128) void main_fb_kernel(
    const float* __restrict__ x1, const float* __restrict__ x2,
    const float* __restrict__ conv_w, const float* __restrict__ conv_b,
    float* __restrict__ ws)
{
    __shared__ float lds[2][19 * 20];
    __shared__ float red[2];

    int blk = blockIdx.x;
    int c = blk & 63;
    int b = blk >> 6;
    int t = threadIdx.x;

    const float* src1 = x1 + (size_t)blk * 361;
    const float* src2 = x2 + (size_t)blk * 361;
    for (int i = t; i < 361; i += 128) {
        int r = i / 19;
        int col = i - r * 19;
        lds[0][r * 20 + col] = src1[i];
        lds[1][r * 20 + col] = src2[i];
    }

    int o = t >> 6;
    int l = t & 63;
    int pi = l >> 3, pj = l & 7;

    const float* wcp = conv_w + c * 36 + o * 18;
    float w0[9], w1[9];
    #pragma unroll
    for (int k = 0; k < 9; k++) { w0[k] = wcp[k]; w1[k] = wcp[9 + k]; }
    float cbv = conv_b[c * 2 + o];
    float A   = ws[WS_A + c * 2 + o];
    float Bs  = ws[WS_B + c * 2 + o];
    float wf  = ws[WS_WF + c * 128 + t];

    __syncthreads();

    float xw[2][4][4];
    int base = (2 * pi) * 20 + 2 * pj;
    #pragma unroll
    for (int ic = 0; ic < 2; ic++)
        #pragma unroll
        for (int r = 0; r < 4; r++)
            #pragma unroll
            for (int cc = 0; cc < 4; cc++)
                xw[ic][r][cc] = lds[ic][base + r * 20 + cc];

    float m = -3.4e38f;
    #pragma unroll
    for (int di = 0; di < 2; di++)
        #pragma unroll
        for (int dj = 0; dj < 2; dj++) {
            float acc = cbv;
            #pragma unroll
            for (int ki = 0; ki < 3; ki++)
                #pragma unroll
                for (int kj = 0; kj < 3; kj++) {
                    acc = fmaf(xw[0][di + ki][dj + kj], w0[ki * 3 + kj], acc);
                    acc = fmaf(xw[1][di + ki][dj + kj], w1[ki * 3 + kj], acc);
                }
            float v = fmaf(A, acc, Bs);
            v = v > 0.f ? v : SLOPE * v;
            m = fmaxf(m, v);
        }

    float contrib = m * wf;
    #pragma unroll
    for (int off = 32; off > 0; off >>= 1)
        contrib += __shfl_down(contrib, off);
    if (l == 0) red[o] = contrib;
    __syncthreads();
    if (t == 0)
        atomicAdd(&ws[WS_LOGIT + b], red[0] + red[1]);
}

__global__ __launch_bounds__(256) void final_fb_kernel(
    const float* __restrict__ ws, const float* __restrict__ b_out,
    float* __restrict__ out)
{
    int b = blockIdx.x * blockDim.x + threadIdx.x;
    if (b >= BATCH) return;
    float bias = b_out[0];
    #pragma unroll
    for (int c = 0; c < CC; c++) bias += ws[WS_WB + c];
    float l = ws[WS_LOGIT + b] + bias;
    out[b] = 1.f / (1.f + expf(-l));
}

extern "C" void kernel_launch(void* const* d_in, const int* in_sizes, int n_in,
                              void* d_out, int out_size, void* d_ws, size_t ws_size,
                              hipStream_t stream) {
    const float* x1     = (const float*)d_in[0];
    const float* x2     = (const float*)d_in[1];
    const float* conv_w = (const float*)d_in[2];
    const float* conv_b = (const float*)d_in[3];
    const float* bn_g   = (const float*)d_in[4];
    const float* bn_b   = (const float*)d_in[5];
    const float* fc1_w  = (const float*)d_in[6];
    const float* fc1_b  = (const float*)d_in[7];
    const float* fc2_w  = (const float*)d_in[8];
    const float* fc2_b  = (const float*)d_in[9];
    const float* w_out  = (const float*)d_in[10];
    const float* b_out  = (const float*)d_in[11];
    float* ws  = (float*)d_ws;
    float* out = (float*)d_out;

    dim3 big(BATCH * 32);            // 2 channels per block
    bool pool_path = ws_size >= WS_NEEDED_BYTES;

    if (pool_path) {
        hipMemsetAsync(d_ws, 0, 8192 * sizeof(float), stream);   // stats replicas
        pass1_kernel<true><<<big, 128, 0, stream>>>(x1, x2, conv_w, conv_b, ws);
        prep_kernel<<<CC, 128, 0, stream>>>(bn_g, bn_b, fc1_w, fc1_b, fc2_w, fc2_b, w_out, ws);
        pass2_kernel<<<BATCH, 256, 0, stream>>>(ws, b_out, out);
    } else {
        hipMemsetAsync(d_ws, 0, 18752 * sizeof(float), stream);  // stats + logits
        pass1_kernel<false><<<big, 128, 0, stream>>>(x1, x2, conv_w, conv_b, ws);
        prep_kernel<<<CC, 128, 0, stream>>>(bn_g, bn_b, fc1_w, fc1_b, fc2_w, fc2_b, w_out, ws);
        main_fb_kernel<<<dim3(BATCH * CC), 128, 0, stream>>>(x1, x2, conv_w, conv_b, ws);
        final_fb_kernel<<<(BATCH + 255) / 256, 256, 0, stream>>>(ws, b_out, out);
    }
}

// Round 7
// 141.214 us; speedup vs baseline: 7.3039x; 1.0757x over previous
//
#include <hip/hip_runtime.h>
#include <math.h>

#define CC    64
#define BATCH 2048
#define EPS   1e-5f
#define SLOPE 0.01f

// ws layout (float indices):
#define WS_SUMR  0        // 32 replicas x 128 (c,o)
#define WS_SQR   4096     // 32 replicas x 128
#define WS_A     8192     // 128
#define WS_B     8320     // 128
#define WS_WF    8448     // 64*128 folded weights
#define WS_WB    16640    // 64 per-channel bias contribution
#define WS_LOGIT 16704    // 2048 (fallback path only)
#define WS_POOL  18944    // 2048*64*128 uint (bf16 mx | bf16 mn), 16B-aligned
#define WS_NEEDED_BYTES ((size_t)(WS_POOL + (size_t)BATCH * CC * 128) * 4)

__device__ inline unsigned bf16rne(float x) {
    unsigned u = __float_as_uint(x);
    return (u + 0x7fffu + ((u >> 16) & 1u)) >> 16;
}

// guaranteed packed f32 FMA: acc = a*b + acc (VOP3P v_pk_fma_f32, CDNA4)
__device__ inline void pkfma(float2& acc, float2 a, float2 b) {
    asm("v_pk_fma_f32 %0, %1, %2, %0" : "+v"(acc) : "v"(a), "v"(b));
}

// ---------------- Pass 1: conv + batch stats (+ pooled bf16 max/min store) ----------------
// One 128-thread block = 2 images (b,c0),(b,c0+1); one wave per image.
// LDS = exact copy of global layout: lds[ic][722] (722 = 2 images x 361).
// Lane l: o=l>>5 (weights half), p=l&31, pi=p>>2, pjp=p&3
//   -> pooled cells (pi, 2pjp), (pi, 2pjp+1): conv rows 2pi..2pi+1, cols 4pjp..4pjp+3.
template<bool STORE>
__global__ __launch_bounds__(128, 4) void pass1_kernel(
    const float* __restrict__ x1, const float* __restrict__ x2,
    const float* __restrict__ conv_w, const float* __restrict__ conv_b,
    float* __restrict__ ws)
{
    __shared__ float lds[2][722];

    int blk = blockIdx.x;            // b*32 + cpair
    int b  = blk >> 5;
    int c0 = (blk & 31) * 2;
    int t  = threadIdx.x;

    // exact-copy staging: 361 float2 per source, zero index math
    const float2* g1 = (const float2*)(x1 + ((size_t)b * 64 + c0) * 361);
    const float2* g2 = (const float2*)(x2 + ((size_t)b * 64 + c0) * 361);
    float2* L0 = (float2*)lds[0];
    float2* L1 = (float2*)lds[1];
    L0[t]       = g1[t];
    L0[t + 128] = g1[t + 128];
    L1[t]       = g2[t];
    L1[t + 128] = g2[t + 128];
    if (t < 105) {
        L0[t + 256] = g1[t + 256];
        L1[t + 256] = g2[t + 256];
    }

    int wv  = t >> 6;               // image index within block (wave id)
    int l   = t & 63;
    int o   = l >> 5;               // output channel (half-wave)
    int p   = l & 31;
    int pi  = p >> 2;
    int pjp = p & 3;
    int c   = c0 + wv;

    // weights as {w,w} pairs (9 float2 loads, 8B-aligned)
    const float2* wp2 = (const float2*)(conv_w + (size_t)(c * 2 + o) * 18);
    float2 wgt[18];
    #pragma unroll
    for (int j = 0; j < 9; j++) {
        float2 pr = wp2[j];
        wgt[2 * j]     = make_float2(pr.x, pr.x);
        wgt[2 * j + 1] = make_float2(pr.y, pr.y);
    }
    float cbv = conv_b[c * 2 + o];

    __syncthreads();

    int ib = wv * 361;                    // image base (words) within lds[ic]
    int lb = ib + pi * 38 + pjp * 4;      // lane window base (row 2pi, col 4pjp)

    // Q[di][g] = {y[2pi+di, 4pjp+2g], y[2pi+di, 4pjp+2g+1]}
    float2 Q00 = make_float2(cbv, cbv), Q01 = make_float2(cbv, cbv);
    float2 Q10 = make_float2(cbv, cbv), Q11 = make_float2(cbv, cbv);

    #pragma unroll
    for (int ic = 0; ic < 2; ic++) {
        const float* P = &lds[ic][lb];
        const float2* wic = &wgt[ic * 9];
        #pragma unroll
        for (int r = 0; r < 4; r++) {
            const float* row = P + 19 * r;
            float x0 = row[0], x1v = row[1], x2v = row[2];
            float x3 = row[3], x4 = row[4], x5v = row[5];
            float2 X0 = make_float2(x0, x1v);
            float2 X1 = make_float2(x1v, x2v);
            float2 X2 = make_float2(x2v, x3);
            float2 X3 = make_float2(x3, x4);
            float2 X4 = make_float2(x4, x5v);
            if (r < 3) {            // di=0, ki=r
                pkfma(Q00, X0, wic[3 * r + 0]);
                pkfma(Q00, X1, wic[3 * r + 1]);
                pkfma(Q00, X2, wic[3 * r + 2]);
                pkfma(Q01, X2, wic[3 * r + 0]);
                pkfma(Q01, X3, wic[3 * r + 1]);
                pkfma(Q01, X4, wic[3 * r + 2]);
            }
            if (r >= 1) {           // di=1, ki=r-1
                int ki = r - 1;
                pkfma(Q10, X0, wic[3 * ki + 0]);
                pkfma(Q10, X1, wic[3 * ki + 1]);
                pkfma(Q10, X2, wic[3 * ki + 2]);
                pkfma(Q11, X2, wic[3 * ki + 0]);
                pkfma(Q11, X3, wic[3 * ki + 1]);
                pkfma(Q11, X4, wic[3 * ki + 2]);
            }
        }
    }

    // stats + pooled max/min (cellA = Q00/Q10, cellB = Q01/Q11)
    float2 sp = make_float2(Q00.x + Q10.x + Q01.x + Q11.x,
                            Q00.y + Q10.y + Q01.y + Q11.y);
    float2 q2 = make_float2(0.f, 0.f);
    pkfma(q2, Q00, Q00); pkfma(q2, Q01, Q01);
    pkfma(q2, Q10, Q10); pkfma(q2, Q11, Q11);
    float s = sp.x + sp.y;
    float q = q2.x + q2.y;

    float mxA = fmaxf(fmaxf(Q00.x, Q00.y), fmaxf(Q10.x, Q10.y));
    float mnA = fminf(fminf(Q00.x, Q00.y), fminf(Q10.x, Q10.y));
    float mxB = fmaxf(fmaxf(Q01.x, Q01.y), fmaxf(Q11.x, Q11.y));
    float mnB = fminf(fminf(Q01.x, Q01.y), fminf(Q11.x, Q11.y));

    if (STORE) {
        unsigned* pool = (unsigned*)(ws + WS_POOL);
        size_t pix = ((size_t)(b * 64 + c)) * 128 + o * 64 + pi * 8 + 2 * pjp;
        uint2 pk;
        pk.x = (bf16rne(mxA) << 16) | bf16rne(mnA);
        pk.y = (bf16rne(mxB) << 16) | bf16rne(mnB);
        *(uint2*)&pool[pix] = pk;
    }

    // border outputs (stats only): rep1 = 32 lanes x 1 output, full width
    {
        int bi = p < 17 ? 16 : p - 17;    // (16,0..16) and (0..14,16)
        int bj = p < 17 ? p  : 16;
        int bw = ib + 19 * bi + bj;
        float accb = cbv;
        #pragma unroll
        for (int ic = 0; ic < 2; ic++)
            #pragma unroll
            for (int ki = 0; ki < 3; ki++)
                #pragma unroll
                for (int kj = 0; kj < 3; kj++)
                    accb = fmaf(lds[ic][bw + 19 * ki + kj], wgt[ic * 9 + ki * 3 + kj].x, accb);
        s += accb; q = fmaf(accb, accb, q);
    }
    // rep2: the single remaining output (15,16), lane p==0
    if (p == 0) {
        int bw = ib + 19 * 15 + 16;
        float accb = cbv;
        #pragma unroll
        for (int ic = 0; ic < 2; ic++)
            #pragma unroll
            for (int ki = 0; ki < 3; ki++)
                #pragma unroll
                for (int kj = 0; kj < 3; kj++)
                    accb = fmaf(lds[ic][bw + 19 * ki + kj], wgt[ic * 9 + ki * 3 + kj].x, accb);
        s += accb; q = fmaf(accb, accb, q);
    }

    // reduce within each 32-lane half
    #pragma unroll
    for (int off = 16; off > 0; off >>= 1) {
        s += __shfl_down(s, off, 32);
        q += __shfl_down(q, off, 32);
    }
    if (p == 0) {
        int rep = b & 31;          // b-derived: 32-way spread per (c,o) slot
        atomicAdd(&ws[WS_SUMR + rep * 128 + c * 2 + o], s);
        atomicAdd(&ws[WS_SQR  + rep * 128 + c * 2 + o], q);
    }
}

// ---------------- Prep: replica-sum stats, BN scale/shift, folded fc weights ----------------
__global__ __launch_bounds__(128) void prep_kernel(
    const float* __restrict__ bn_g, const float* __restrict__ bn_b,
    const float* __restrict__ fc1_w, const float* __restrict__ fc1_b,
    const float* __restrict__ fc2_w, const float* __restrict__ fc2_b,
    const float* __restrict__ w_out,
    float* __restrict__ ws)
{
    int c = blockIdx.x;
    int f = threadIdx.x;

    float wsum = 0.f;
    #pragma unroll
    for (int h = 0; h < 8; h++)
        wsum += fc2_w[c * 8 + h] * fc1_w[(c * 8 + h) * 128 + f];
    ws[WS_WF + c * 128 + f] = w_out[c] * wsum;

    if (f == 0) {
        float bsum = fc2_b[c];
        #pragma unroll
        for (int h = 0; h < 8; h++)
            bsum += fc2_w[c * 8 + h] * fc1_b[c * 8 + h];
        ws[WS_WB + c] = w_out[c] * bsum;
    }
    if (f < 2) {
        int idx = c * 2 + f;
        float s = 0.f, q = 0.f;
        for (int r = 0; r < 32; r++) {
            s += ws[WS_SUMR + r * 128 + idx];
            q += ws[WS_SQR  + r * 128 + idx];
        }
        const float N = 2048.0f * 289.0f;
        float mean = s / N;
        float var  = q / N - mean * mean;
        float inv  = rsqrtf(var + EPS);
        float A    = bn_g[idx] * inv;
        ws[WS_A + idx] = A;
        ws[WS_B + idx] = bn_b[idx] - mean * A;
    }
}

// ---------------- Pass 2: stream bf16 pool -> logits -> sigmoid ----------------
__global__ __launch_bounds__(256) void pass2_kernel(
    const float* __restrict__ ws, const float* __restrict__ b_out,
    float* __restrict__ out)
{
    __shared__ float red[4];
    int b = blockIdx.x;
    int t = threadIdx.x;
    const uint4* pool = (const uint4*)(ws + WS_POOL) + (size_t)b * 2048;

    float partial = (t < 64) ? ws[WS_WB + t] : 0.f;
    if (t == 0) partial += b_out[0];

    #pragma unroll
    for (int i = 0; i < 8; i++) {
        uint4 p = pool[t + i * 256];
        int k0 = (t + i * 256) * 4;
        float A  = ws[WS_A + (k0 >> 6)];
        float Bs = ws[WS_B + (k0 >> 6)];
        const float4 wf = *(const float4*)&ws[WS_WF + k0];
        unsigned uu[4] = { p.x, p.y, p.z, p.w };
        float wfv[4] = { wf.x, wf.y, wf.z, wf.w };
        #pragma unroll
        for (int j = 0; j < 4; j++) {
            float mx = __uint_as_float(uu[j] & 0xffff0000u);
            float mn = __uint_as_float(uu[j] << 16);
            float val = A > 0.f ? mx : mn;
            float v = fmaf(A, val, Bs);
            v = v > 0.f ? v : SLOPE * v;
            partial = fmaf(v, wfv[j], partial);
        }
    }

    #pragma unroll
    for (int off = 32; off > 0; off >>= 1)
        partial += __shfl_down(partial, off);
    if ((t & 63) == 0) red[t >> 6] = partial;
    __syncthreads();
    if (t == 0) {
        float lsum = red[0] + red[1] + red[2] + red[3];
        out[b] = 1.f / (1.f + expf(-lsum));
    }
}

// ---------------- Fallback path (small ws): recompute conv with BN applied ----------------
__global__ __launch_bounds__(128) void main_fb_kernel(
    const float* __restrict__ x1, const float* __restrict__ x2,
    const float* __restrict__ conv_w, const float* __restrict__ conv_b,
    float* __restrict__ ws)
{
    __shared__ float lds[2][19 * 20];
    __shared__ float red[2];

    int blk = blockIdx.x;
    int c = blk & 63;
    int b = blk >> 6;
    int t = threadIdx.x;

    const float* src1 = x1 + (size_t)blk * 361;
    const float* src2 = x2 + (size_t)blk * 361;
    for (int i = t; i < 361; i += 128) {
        int r = i / 19;
        int col = i - r * 19;
        lds[0][r * 20 + col] = src1[i];
        lds[1][r * 20 + col] = src2[i];
    }

    int o = t >> 6;
    int l = t & 63;
    int pi = l >> 3, pj = l & 7;

    const float* wcp = conv_w + c * 36 + o * 18;
    float w0[9], w1[9];
    #pragma unroll
    for (int k = 0; k < 9; k++) { w0[k] = wcp[k]; w1[k] = wcp[9 + k]; }
    float cbv = conv_b[c * 2 + o];
    float A   = ws[WS_A + c * 2 + o];
    float Bs  = ws[WS_B + c * 2 + o];
    float wf  = ws[WS_WF + c * 128 + t];

    __syncthreads();

    float xw[2][4][4];
    int base = (2 * pi) * 20 + 2 * pj;
    #pragma unroll
    for (int ic = 0; ic < 2; ic++)
        #pragma unroll
        for (int r = 0; r < 4; r++)
            #pragma unroll
            for (int cc = 0; cc < 4; cc++)
                xw[ic][r][cc] = lds[ic][base + r * 20 + cc];

    float m = -3.4e38f;
    #pragma unroll
    for (int di = 0; di < 2; di++)
        #pragma unroll
        for (int dj = 0; dj < 2; dj++) {
            float acc = cbv;
            #pragma unroll
            for (int ki = 0; ki < 3; ki++)
                #pragma unroll
                for (int kj = 0; kj < 3; kj++) {
                    acc = fmaf(xw[0][di + ki][dj + kj], w0[ki * 3 + kj], acc);
                    acc = fmaf(xw[1][di + ki][dj + kj], w1[ki * 3 + kj], acc);
                }
            float v = fmaf(A, acc, Bs);
            v = v > 0.f ? v : SLOPE * v;
            m = fmaxf(m, v);
        }

    float contrib = m * wf;
    #pragma unroll
    for (int off = 32; off > 0; off >>= 1)
        contrib += __shfl_down(contrib, off);
    if (l == 0) red[o] = contrib;
    __syncthreads();
    if (t == 0)
        atomicAdd(&ws[WS_LOGIT + b], red[0] + red[1]);
}

__global__ __launch_bounds__(256) void final_fb_kernel(
    const float* __restrict__ ws, const float* __restrict__ b_out,
    float* __restrict__ out)
{
    int b = blockIdx.x * blockDim.x + threadIdx.x;
    if (b >= BATCH) return;
    float bias = b_out[0];
    #pragma unroll
    for (int c = 0; c < CC; c++) bias += ws[WS_WB + c];
    float l = ws[WS_LOGIT + b] + bias;
    out[b] = 1.f / (1.f + expf(-l));
}

extern "C" void kernel_launch(void* const* d_in, const int* in_sizes, int n_in,
                              void* d_out, int out_size, void* d_ws, size_t ws_size,
                              hipStream_t stream) {
    const float* x1     = (const float*)d_in[0];
    const float* x2     = (const float*)d_in[1];
    const float* conv_w = (const float*)d_in[2];
    const float* conv_b = (const float*)d_in[3];
    const float* bn_g   = (const float*)d_in[4];
    const float* bn_b   = (const float*)d_in[5];
    const float* fc1_w  = (const float*)d_in[6];
    const float* fc1_b  = (const float*)d_in[7];
    const float* fc2_w  = (const float*)d_in[8];
    const float* fc2_b  = (const float*)d_in[9];
    const float* w_out  = (const float*)d_in[10];
    const float* b_out  = (const float*)d_in[11];
    float* ws  = (float*)d_ws;
    float* out = (float*)d_out;

    dim3 big(BATCH * 32);            // 2 channels per block
    bool pool_path = ws_size >= WS_NEEDED_BYTES;

    if (pool_path) {
        hipMemsetAsync(d_ws, 0, 8192 * sizeof(float), stream);   // stats replicas
        pass1_kernel<true><<<big, 128, 0, stream>>>(x1, x2, conv_w, conv_b, ws);
        prep_kernel<<<CC, 128, 0, stream>>>(bn_g, bn_b, fc1_w, fc1_b, fc2_w, fc2_b, w_out, ws);
        pass2_kernel<<<BATCH, 256, 0, stream>>>(ws, b_out, out);
    } else {
        hipMemsetAsync(d_ws, 0, 18752 * sizeof(float), stream);  // stats + logits
        pass1_kernel<false><<<big, 128, 0, stream>>>(x1, x2, conv_w, conv_b, ws);
        prep_kernel<<<CC, 128, 0, stream>>>(bn_g, bn_b, fc1_w, fc1_b, fc2_w, fc2_b, w_out, ws);
        main_fb_kernel<<<dim3(BATCH * CC), 128, 0, stream>>>(x1, x2, conv_w, conv_b, ws);
        final_fb_kernel<<<(BATCH + 255) / 256, 256, 0, stream>>>(ws, b_out, out);
    }
}

// Round 8
// 113.175 us; speedup vs baseline: 9.1134x; 1.2478x over previous
//
#include <hip/hip_runtime.h>
#include <math.h>

#define CC    64
#define BATCH 2048
#define EPS   1e-5f
#define SLOPE 0.01f

// ws layout (float indices):
#define WS_SUMR  0        // 32 replicas x 128 (c,o)
#define WS_SQR   4096     // 32 replicas x 128
#define WS_A     8192     // 128
#define WS_B     8320     // 128
#define WS_WF    8448     // 64*128 folded weights
#define WS_WB    16640    // 64 per-channel bias contribution
#define WS_LOGIT 16704    // 2048 (fallback path only)
#define WS_POOL  18944    // 2048*64*128 uint (bf16 mx | bf16 mn), 16B-aligned
#define WS_NEEDED_BYTES ((size_t)(WS_POOL + (size_t)BATCH * CC * 128) * 4)

__device__ inline unsigned bf16rne(float x) {
    unsigned u = __float_as_uint(x);
    return (u + 0x7fffu + ((u >> 16) & 1u)) >> 16;
}

// guaranteed packed f32 FMA: acc = a*b + acc (VOP3P v_pk_fma_f32, CDNA4)
__device__ inline void pkfma(float2& acc, float2 a, float2 b) {
    asm("v_pk_fma_f32 %0, %1, %2, %0" : "+v"(acc) : "v"(a), "v"(b));
}

// ---------------- Pass 1: conv + batch stats (+ pooled bf16 max/min store) ----------------
// One 64-thread block = one wave = 2 images (b,c0),(b,c0+1).
// LDS: [src][img*380 + row*20 + col]  (rows padded 19->20 so every window base is 16B aligned).
// Lane t: img=t>>5, o=(t>>4)&1, p=t&15, pi=p>>1, pjp=p&1
//   -> 4 pooled cells (pi, 4pjp..4pjp+3): conv rows 2pi..2pi+1, conv cols 8pjp..8pjp+7,
//      input window rows 2pi..2pi+3, cols 8pjp..8pjp+9 (10 words, aligned).
template<bool STORE>
__global__ __launch_bounds__(64, 4) void pass1_kernel(
    const float* __restrict__ x1, const float* __restrict__ x2,
    const float* __restrict__ conv_w, const float* __restrict__ conv_b,
    float* __restrict__ ws)
{
    __shared__ __align__(16) float lds[2][760];

    int blk = blockIdx.x;            // b*32 + cpair
    int b  = blk >> 5;
    int c0 = (blk & 31) * 2;
    int t  = threadIdx.x;            // 0..63

    // staging: 361 float2 per source; write idx = e + e/19 (img pad falls out)
    const float2* g1 = (const float2*)(x1 + ((size_t)b * 64 + c0) * 361);
    const float2* g2 = (const float2*)(x2 + ((size_t)b * 64 + c0) * 361);
    #pragma unroll
    for (int sl = 0; sl < 6; sl++) {
        int g = t + 64 * sl;
        if (sl < 5 || g < 361) {
            float2 v1 = g1[g];
            float2 v2 = g2[g];
            unsigned e  = 2u * g;
            unsigned r0 = (e * 110377u) >> 21;          // e/19 (exact for e<=721)
            unsigned r1 = ((e + 1u) * 110377u) >> 21;
            int i0 = e + r0;
            int i1 = e + 1 + r1;
            lds[0][i0] = v1.x; lds[0][i1] = v1.y;
            lds[1][i0] = v2.x; lds[1][i1] = v2.y;
        }
    }

    int img = t >> 5;
    int u   = t & 31;
    int o   = u >> 4;
    int p   = u & 15;
    int pi  = p >> 1;
    int pjp = p & 1;
    int c   = c0 + img;

    // weights as {w,w} pairs
    const float2* wp2 = (const float2*)(conv_w + (size_t)(c * 2 + o) * 18);
    float2 wgt[18];
    #pragma unroll
    for (int j = 0; j < 9; j++) {
        float2 pr = wp2[j];
        wgt[2 * j]     = make_float2(pr.x, pr.x);
        wgt[2 * j + 1] = make_float2(pr.y, pr.y);
    }
    float cbv = conv_b[c * 2 + o];

    __syncthreads();

    // A[di][k] = conv outputs {row 2pi+di, cols 8pjp+2k, 8pjp+2k+1} (cell k of 4)
    float2 A[2][4];
    #pragma unroll
    for (int di = 0; di < 2; di++)
        #pragma unroll
        for (int k = 0; k < 4; k++)
            A[di][k] = make_float2(cbv, cbv);

    int wb = img * 380 + pi * 40 + pjp * 8;   // window base (mod 4 == 0)

    #pragma unroll
    for (int ic = 0; ic < 2; ic++) {
        const float* plane = &lds[ic][wb];
        const float2* wic = &wgt[ic * 9];
        #pragma unroll
        for (int r = 0; r < 4; r++) {
            const float* row = plane + 20 * r;
            float4 a4 = *(const float4*)(row);       // x0..x3
            float4 b4 = *(const float4*)(row + 4);   // x4..x7
            float2 c2 = *(const float2*)(row + 8);   // x8,x9
            float2 P[9];
            P[0] = make_float2(a4.x, a4.y);
            P[1] = make_float2(a4.y, a4.z);
            P[2] = make_float2(a4.z, a4.w);
            P[3] = make_float2(a4.w, b4.x);
            P[4] = make_float2(b4.x, b4.y);
            P[5] = make_float2(b4.y, b4.z);
            P[6] = make_float2(b4.z, b4.w);
            P[7] = make_float2(b4.w, c2.x);
            P[8] = make_float2(c2.x, c2.y);
            #pragma unroll
            for (int di = 0; di < 2; di++) {
                int ki = r - di;
                if (ki < 0 || ki > 2) continue;
                #pragma unroll
                for (int k = 0; k < 4; k++)
                    #pragma unroll
                    for (int kj = 0; kj < 3; kj++)
                        pkfma(A[di][k], P[2 * k + kj], wic[3 * ki + kj]);
            }
        }
    }

    // stats + pooled max/min (cell k: A[0][k], A[1][k])
    const float2 one2 = make_float2(1.f, 1.f);
    float2 sp = make_float2(0.f, 0.f), q2 = make_float2(0.f, 0.f);
    #pragma unroll
    for (int di = 0; di < 2; di++)
        #pragma unroll
        for (int k = 0; k < 4; k++) {
            pkfma(sp, A[di][k], one2);
            pkfma(q2, A[di][k], A[di][k]);
        }
    float s = sp.x + sp.y;
    float q = q2.x + q2.y;

    if (STORE) {
        unsigned pk[4];
        #pragma unroll
        for (int k = 0; k < 4; k++) {
            float mx = fmaxf(fmaxf(A[0][k].x, A[0][k].y), fmaxf(A[1][k].x, A[1][k].y));
            float mn = fminf(fminf(A[0][k].x, A[0][k].y), fminf(A[1][k].x, A[1][k].y));
            pk[k] = (bf16rne(mx) << 16) | bf16rne(mn);
        }
        uint4* pool4 = (uint4*)(ws + WS_POOL);
        pool4[((size_t)(b * 64 + c)) * 32 + o * 16 + pi * 2 + pjp] =
            make_uint4(pk[0], pk[1], pk[2], pk[3]);
    }

    // border outputs (stats only), 33 per (img,o): (16,0..16) and (0..14,16) via 2 reps, + (15,16)
    int ibase = img * 380;
    #pragma unroll
    for (int rep = 0; rep < 2; rep++) {
        int bidx = p + 16 * rep;
        int bi = bidx < 17 ? 16 : bidx - 17;
        int bj = bidx < 17 ? bidx : 16;
        int bw = ibase + 20 * bi + bj;
        float accb = cbv;
        #pragma unroll
        for (int ic = 0; ic < 2; ic++)
            #pragma unroll
            for (int ki = 0; ki < 3; ki++)
                #pragma unroll
                for (int kj = 0; kj < 3; kj++)
                    accb = fmaf(lds[ic][bw + 20 * ki + kj], wgt[ic * 9 + ki * 3 + kj].x, accb);
        s += accb; q = fmaf(accb, accb, q);
    }
    if (p == 0) {   // (15,16)
        int bw = ibase + 20 * 15 + 16;
        float accb = cbv;
        #pragma unroll
        for (int ic = 0; ic < 2; ic++)
            #pragma unroll
            for (int ki = 0; ki < 3; ki++)
                #pragma unroll
                for (int kj = 0; kj < 3; kj++)
                    accb = fmaf(lds[ic][bw + 20 * ki + kj], wgt[ic * 9 + ki * 3 + kj].x, accb);
        s += accb; q = fmaf(accb, accb, q);
    }

    // reduce within each 16-lane (img,o) group
    #pragma unroll
    for (int off = 8; off > 0; off >>= 1) {
        s += __shfl_down(s, off, 16);
        q += __shfl_down(q, off, 16);
    }
    if (p == 0) {
        int rep = b & 31;
        atomicAdd(&ws[WS_SUMR + rep * 128 + c * 2 + o], s);
        atomicAdd(&ws[WS_SQR  + rep * 128 + c * 2 + o], q);
    }
}

// ---------------- Prep: replica-sum stats, BN scale/shift, folded fc weights ----------------
__global__ __launch_bounds__(128) void prep_kernel(
    const float* __restrict__ bn_g, const float* __restrict__ bn_b,
    const float* __restrict__ fc1_w, const float* __restrict__ fc1_b,
    const float* __restrict__ fc2_w, const float* __restrict__ fc2_b,
    const float* __restrict__ w_out,
    float* __restrict__ ws)
{
    int c = blockIdx.x;
    int f = threadIdx.x;

    float wsum = 0.f;
    #pragma unroll
    for (int h = 0; h < 8; h++)
        wsum += fc2_w[c * 8 + h] * fc1_w[(c * 8 + h) * 128 + f];
    ws[WS_WF + c * 128 + f] = w_out[c] * wsum;

    if (f == 0) {
        float bsum = fc2_b[c];
        #pragma unroll
        for (int h = 0; h < 8; h++)
            bsum += fc2_w[c * 8 + h] * fc1_b[c * 8 + h];
        ws[WS_WB + c] = w_out[c] * bsum;
    }
    if (f < 2) {
        int idx = c * 2 + f;
        float s = 0.f, q = 0.f;
        for (int r = 0; r < 32; r++) {
            s += ws[WS_SUMR + r * 128 + idx];
            q += ws[WS_SQR  + r * 128 + idx];
        }
        const float N = 2048.0f * 289.0f;
        float mean = s / N;
        float var  = q / N - mean * mean;
        float inv  = rsqrtf(var + EPS);
        float A    = bn_g[idx] * inv;
        ws[WS_A + idx] = A;
        ws[WS_B + idx] = bn_b[idx] - mean * A;
    }
}

// ---------------- Pass 2: stream bf16 pool -> logits -> sigmoid ----------------
__global__ __launch_bounds__(256) void pass2_kernel(
    const float* __restrict__ ws, const float* __restrict__ b_out,
    float* __restrict__ out)
{
    __shared__ float red[4];
    int b = blockIdx.x;
    int t = threadIdx.x;
    const uint4* pool = (const uint4*)(ws + WS_POOL) + (size_t)b * 2048;

    float partial = (t < 64) ? ws[WS_WB + t] : 0.f;
    if (t == 0) partial += b_out[0];

    #pragma unroll
    for (int i = 0; i < 8; i++) {
        uint4 p = pool[t + i * 256];
        int k0 = (t + i * 256) * 4;
        float A  = ws[WS_A + (k0 >> 6)];
        float Bs = ws[WS_B + (k0 >> 6)];
        const float4 wf = *(const float4*)&ws[WS_WF + k0];
        unsigned uu[4] = { p.x, p.y, p.z, p.w };
        float wfv[4] = { wf.x, wf.y, wf.z, wf.w };
        #pragma unroll
        for (int j = 0; j < 4; j++) {
            float mx = __uint_as_float(uu[j] & 0xffff0000u);
            float mn = __uint_as_float(uu[j] << 16);
            float val = A > 0.f ? mx : mn;
            float v = fmaf(A, val, Bs);
            v = v > 0.f ? v : SLOPE * v;
            partial = fmaf(v, wfv[j], partial);
        }
    }

    #pragma unroll
    for (int off = 32; off > 0; off >>= 1)
        partial += __shfl_down(partial, off);
    if ((t & 63) == 0) red[t >> 6] = partial;
    __syncthreads();
    if (t == 0) {
        float lsum = red[0] + red[1] + red[2] + red[3];
        out[b] = 1.f / (1.f + expf(-lsum));
    }
}

// ---------------- Fallback path (small ws): recompute conv with BN applied ----------------
__global__ __launch_bounds__(128) void main_fb_kernel(
    const float* __restrict__ x1, const float* __restrict__ x2,
    const float* __restrict__ conv_w, const float* __restrict__ conv_b,
    float* __restrict__ ws)
{
    __shared__ float lds[2][19 * 20];
    __shared__ float red[2];

    int blk = blockIdx.x;
    int c = blk & 63;
    int b = blk >> 6;
    int t = threadIdx.x;

    const float* src1 = x1 + (size_t)blk * 361;
    const float* src2 = x2 + (size_t)blk * 361;
    for (int i = t; i < 361; i += 128) {
        int r = i / 19;
        int col = i - r * 19;
        lds[0][r * 20 + col] = src1[i];
        lds[1][r * 20 + col] = src2[i];
    }

    int o = t >> 6;
    int l = t & 63;
    int pi = l >> 3, pj = l & 7;

    const float* wcp = conv_w + c * 36 + o * 18;
    float w0[9], w1[9];
    #pragma unroll
    for (int k = 0; k < 9; k++) { w0[k] = wcp[k]; w1[k] = wcp[9 + k]; }
    float cbv = conv_b[c * 2 + o];
    float A   = ws[WS_A + c * 2 + o];
    float Bs  = ws[WS_B + c * 2 + o];
    float wf  = ws[WS_WF + c * 128 + t];

    __syncthreads();

    float xw[2][4][4];
    int base = (2 * pi) * 20 + 2 * pj;
    #pragma unroll
    for (int ic = 0; ic < 2; ic++)
        #pragma unroll
        for (int r = 0; r < 4; r++)
            #pragma unroll
            for (int cc = 0; cc < 4; cc++)
                xw[ic][r][cc] = lds[ic][base + r * 20 + cc];

    float m = -3.4e38f;
    #pragma unroll
    for (int di = 0; di < 2; di++)
        #pragma unroll
        for (int dj = 0; dj < 2; dj++) {
            float acc = cbv;
            #pragma unroll
            for (int ki = 0; ki < 3; ki++)
                #pragma unroll
                for (int kj = 0; kj < 3; kj++) {
                    acc = fmaf(xw[0][di + ki][dj + kj], w0[ki * 3 + kj], acc);
                    acc = fmaf(xw[1][di + ki][dj + kj], w1[ki * 3 + kj], acc);
                }
            float v = fmaf(A, acc, Bs);
            v = v > 0.f ? v : SLOPE * v;
            m = fmaxf(m, v);
        }

    float contrib = m * wf;
    #pragma unroll
    for (int off = 32; off > 0; off >>= 1)
        contrib += __shfl_down(contrib, off);
    if (l == 0) red[o] = contrib;
    __syncthreads();
    if (t == 0)
        atomicAdd(&ws[WS_LOGIT + b], red[0] + red[1]);
}

__global__ __launch_bounds__(256) void final_fb_kernel(
    const float* __restrict__ ws, const float* __restrict__ b_out,
    float* __restrict__ out)
{
    int b = blockIdx.x * blockDim.x + threadIdx.x;
    if (b >= BATCH) return;
    float bias = b_out[0];
    #pragma unroll
    for (int c = 0; c < CC; c++) bias += ws[WS_WB + c];
    float l = ws[WS_LOGIT + b] + bias;
    out[b] = 1.f / (1.f + expf(-l));
}

extern "C" void kernel_launch(void* const* d_in, const int* in_sizes, int n_in,
                              void* d_out, int out_size, void* d_ws, size_t ws_size,
                              hipStream_t stream) {
    const float* x1     = (const float*)d_in[0];
    const float* x2     = (const float*)d_in[1];
    const float* conv_w = (const float*)d_in[2];
    const float* conv_b = (const float*)d_in[3];
    const float* bn_g   = (const float*)d_in[4];
    const float* bn_b   = (const float*)d_in[5];
    const float* fc1_w  = (const float*)d_in[6];
    const float* fc1_b  = (const float*)d_in[7];
    const float* fc2_w  = (const float*)d_in[8];
    const float* fc2_b  = (const float*)d_in[9];
    const float* w_out  = (const float*)d_in[10];
    const float* b_out  = (const float*)d_in[11];
    float* ws  = (float*)d_ws;
    float* out = (float*)d_out;

    dim3 big(BATCH * 32);            // 1 wave per block, 2 images per wave
    bool pool_path = ws_size >= WS_NEEDED_BYTES;

    if (pool_path) {
        hipMemsetAsync(d_ws, 0, 8192 * sizeof(float), stream);   // stats replicas
        pass1_kernel<true><<<big, 64, 0, stream>>>(x1, x2, conv_w, conv_b, ws);
        prep_kernel<<<CC, 128, 0, stream>>>(bn_g, bn_b, fc1_w, fc1_b, fc2_w, fc2_b, w_out, ws);
        pass2_kernel<<<BATCH, 256, 0, stream>>>(ws, b_out, out);
    } else {
        hipMemsetAsync(d_ws, 0, 18752 * sizeof(float), stream);  // stats + logits
        pass1_kernel<false><<<big, 64, 0, stream>>>(x1, x2, conv_w, conv_b, ws);
        prep_kernel<<<CC, 128, 0, stream>>>(bn_g, bn_b, fc1_w, fc1_b, fc2_w, fc2_b, w_out, ws);
        main_fb_kernel<<<dim3(BATCH * CC), 128, 0, stream>>>(x1, x2, conv_w, conv_b, ws);
        final_fb_kernel<<<(BATCH + 255) / 256, 256, 0, stream>>>(ws, b_out, out);
    }
}